// Round 16
// baseline (141.393 us; speedup 1.0000x reference)
//
#include <hip/hip_runtime.h>
#include <cstdint>

#define N_WIRES 14
#define N_OPS   50
#define NSTATE  (1 << N_WIRES)   // 16384
#define BSZ     256
#define BLOCK   1024
#define LATENT  8
#define NCLMAX  50

// ---------------- host-side numpy RNG (verified: round-13 PASS, winner mapping m=1) ----------------
namespace nprng {
typedef unsigned __int128 u128;
static const u128 PCG_MULT = (((u128)2549297995355413924ULL) << 64) | 4865540595714422341ULL;

struct PCG64 { u128 state, inc; bool has32; uint32_t buf32; };

static inline uint64_t n64(PCG64 &s) {
  s.state = s.state * PCG_MULT + s.inc;
  uint64_t x = (uint64_t)(s.state >> 64) ^ (uint64_t)s.state;
  unsigned r = (unsigned)(s.state >> 122);
  return (x >> (r & 63)) | (x << ((64 - r) & 63));
}
static inline uint32_t n32(PCG64 &s) {
  if (s.has32) { s.has32 = false; return s.buf32; }
  uint64_t n = n64(s);
  s.has32 = true; s.buf32 = (uint32_t)(n >> 32);
  return (uint32_t)n;
}
static PCG64 seedseq(uint32_t entropy) {
  const uint32_t INIT_A = 0x43b0d7e5u, MULT_A = 0x931e8875u;
  const uint32_t INIT_B = 0x8b51f9ddu, MULT_B = 0x58f38dedu;
  const uint32_t MIX_L = 0xca01f9ddu, MIX_R = 0x4973f715u;
  uint32_t pool[4];
  uint32_t hc = INIT_A;
  auto hashmix = [&](uint32_t v) -> uint32_t {
    v ^= hc; hc *= MULT_A; v *= hc; v ^= v >> 16; return v;
  };
  auto mixf = [&](uint32_t x, uint32_t y) -> uint32_t {
    uint32_t r = x * MIX_L - y * MIX_R;   // multiply-SUBTRACT (the verified fix)
    r ^= r >> 16; return r;
  };
  pool[0] = hashmix(entropy);
  for (int i = 1; i < 4; i++) pool[i] = hashmix(0u);
  for (int s = 0; s < 4; s++)
    for (int d = 0; d < 4; d++)
      if (s != d) pool[d] = mixf(pool[d], hashmix(pool[s]));
  uint32_t w[8];
  uint32_t hb = INIT_B;
  for (int i = 0; i < 8; i++) {
    uint32_t dv = pool[i & 3];
    dv ^= hb; hb *= MULT_B; dv *= hb; dv ^= dv >> 16; w[i] = dv;
  }
  uint64_t v0 = (uint64_t)w[0] | ((uint64_t)w[1] << 32);
  uint64_t v1 = (uint64_t)w[2] | ((uint64_t)w[3] << 32);
  uint64_t v2 = (uint64_t)w[4] | ((uint64_t)w[5] << 32);
  uint64_t v3 = (uint64_t)w[6] | ((uint64_t)w[7] << 32);
  PCG64 r;
  u128 initstate = ((u128)v0 << 64) | v1;
  u128 initseq   = ((u128)v2 << 64) | v3;
  r.inc = (initseq << 1) | 1;
  r.state = 0;
  r.state = r.state * PCG_MULT + r.inc;
  r.state += initstate;
  r.state = r.state * PCG_MULT + r.inc;
  r.has32 = false; r.buf32 = 0;
  return r;
}
static inline uint32_t lem32(PCG64 &r, uint32_t rmax) {
  uint32_t ex = rmax + 1u;
  uint64_t m = (uint64_t)n32(r) * ex;
  uint32_t lo = (uint32_t)m;
  if (lo < ex) {
    uint32_t t = (0xFFFFFFFFu - rmax) % ex;
    while (lo < t) { m = (uint64_t)n32(r) * ex; lo = (uint32_t)m; }
  }
  return (uint32_t)(m >> 32);
}
// winner mapping m=1 (round-14 decode)
static void gatespec(int *gt, int *g0, int *g1) {
  PCG64 r = seedseq(1234u);
  for (int i = 0; i < N_OPS; i++) gt[i] = (int)lem32(r, 3);
  for (int i = 0; i < N_OPS; i++) {
    if (gt[i] < 3) { g0[i] = (int)lem32(r, 13); g1[i] = -1; continue; }
    uint32_t a = lem32(r, 12);
    uint32_t v = lem32(r, 13);
    uint32_t b = (v == a) ? 13u : v;
    uint32_t j = lem32(r, 1);
    if (j == 0) { uint32_t t = a; a = b; b = t; }
    g0[i] = (int)a; g1[i] = (int)b;
  }
}
} // namespace nprng

// ---------------- cluster schedule (kernel arg, by value) ----------------
struct Sched {
  int ncl;
  int8_t  cpos[NCLMAX * 4];   // 4 sorted-ascending bit positions per cluster
  int8_t  cng[NCLMAX];        // gates per cluster
  uint16_t gpk[N_OPS];        // packed: type | la<<2 | lt<<4 | gidx<<6
};

static void build_sched(Sched &S) {
  int gt[N_OPS], g0[N_OPS], g1[N_OPS];
  nprng::gatespec(gt, g0, g1);

  bool done[N_OPS] = {false};
  int nsched = 0, ncl = 0, gcount = 0;
  while (nsched < N_OPS) {
    int posv[4], posn = 0;
    int clg[N_OPS], ncg = 0;
    bool progress = true;
    while (progress) {
      progress = false;
      for (int i = 0; i < N_OPS; i++) {
        if (done[i]) continue;
        bool avail = true;
        for (int j = 0; j < i && avail; j++) {
          if (done[j]) continue;
          if (g0[j] == g0[i] || (g1[i] >= 0 && g0[j] == g1[i])) avail = false;
          else if (g1[j] >= 0 && (g1[j] == g0[i] || (g1[i] >= 0 && g1[j] == g1[i]))) avail = false;
        }
        if (!avail) continue;
        int p0 = 13 - g0[i];
        int p1 = (g1[i] >= 0) ? (13 - g1[i]) : -1;
        bool h0 = false, h1 = (p1 < 0);
        for (int k = 0; k < posn; k++) {
          if (posv[k] == p0) h0 = true;
          if (p1 >= 0 && posv[k] == p1) h1 = true;
        }
        int need = (h0 ? 0 : 1) + ((p1 >= 0 && !h1) ? 1 : 0);
        if (posn + need > 4) continue;
        if (!h0) posv[posn++] = p0;
        if (p1 >= 0 && !h1) posv[posn++] = p1;
        clg[ncg++] = i;
        done[i] = true; nsched++; progress = true;
      }
    }
    for (int p = 0; posn < 4 && p < 14; p++) {
      bool used = false;
      for (int k = 0; k < posn; k++) if (posv[k] == p) used = true;
      if (!used) posv[posn++] = p;
    }
    // sort ascending
    for (int a = 0; a < 3; a++)
      for (int b2 = a + 1; b2 < 4; b2++)
        if (posv[b2] < posv[a]) { int t = posv[a]; posv[a] = posv[b2]; posv[b2] = t; }
    for (int k = 0; k < 4; k++) S.cpos[ncl * 4 + k] = (int8_t)posv[k];
    S.cng[ncl] = (int8_t)ncg;
    for (int e = 0; e < ncg; e++) {
      int i = clg[e];
      int pa = 13 - g0[i], la = 0;
      for (int k = 0; k < 4; k++) if (posv[k] == pa) la = k;
      int lt = 0;
      if (g1[i] >= 0) {
        int pt = 13 - g1[i];
        for (int k = 0; k < 4; k++) if (posv[k] == pt) lt = k;
      }
      S.gpk[gcount++] = (uint16_t)(gt[i] | (la << 2) | (lt << 4) | (i << 6));
    }
    ncl++;
  }
  S.ncl = ncl;
}

// ---------------- device kernel ----------------
#define RXP(I0, I1) { float2 a0 = A[I0], a1 = A[I1]; \
  A[I0] = make_float2(cc * a0.x + ss * a1.y, cc * a0.y - ss * a1.x); \
  A[I1] = make_float2(cc * a1.x + ss * a0.y, cc * a1.y - ss * a0.x); }
#define RYP(I0, I1) { float2 a0 = A[I0], a1 = A[I1]; \
  A[I0] = make_float2(cc * a0.x - ss * a1.x, cc * a0.y - ss * a1.y); \
  A[I1] = make_float2(ss * a0.x + cc * a1.x, ss * a0.y + cc * a1.y); }
#define RZP(I0, I1) { float2 a0 = A[I0], a1 = A[I1]; \
  A[I0] = make_float2(cc * a0.x + ss * a0.y, cc * a0.y - ss * a0.x); \
  A[I1] = make_float2(cc * a1.x - ss * a1.y, cc * a1.y + ss * a1.x); }

#define SW1(OP) switch (la) { \
  case 0: OP(0,1) OP(2,3) OP(4,5) OP(6,7) OP(8,9) OP(10,11) OP(12,13) OP(14,15) break; \
  case 1: OP(0,2) OP(1,3) OP(4,6) OP(5,7) OP(8,10) OP(9,11) OP(12,14) OP(13,15) break; \
  case 2: OP(0,4) OP(1,5) OP(2,6) OP(3,7) OP(8,12) OP(9,13) OP(10,14) OP(11,15) break; \
  default: OP(0,8) OP(1,9) OP(2,10) OP(3,11) OP(4,12) OP(5,13) OP(6,14) OP(7,15) break; }

// __launch_bounds__(1024, 4): LDS (132 KB) caps us at 1 block/CU = 4 waves/SIMD anyway,
// so allow 128 VGPRs/thread. Round-15's plain (1024) capped VGPRs at 64 -> A/idxs/part
// spilled to scratch -> 690 MB HBM traffic/dispatch (56% of peak BW). This is the fix.
__global__ __launch_bounds__(BLOCK, 4) void qae_k(
    const float* __restrict__ x, const float* __restrict__ rlp,
    float* __restrict__ out, Sched S)
{
  __shared__ float2 st[NSTATE];
  __shared__ float encc[N_WIRES], encs[N_WIRES], gc[N_OPS], gs[N_OPS];
  const int b = blockIdx.x, tid = threadIdx.x;

  if (tid < N_WIRES) {
    float a = 0.5f * x[b * N_WIRES + tid];
    encc[tid] = cosf(a); encs[tid] = sinf(a);
  } else if (tid >= 64 && tid < 64 + N_OPS) {
    int g = tid - 64;
    float a = 0.5f * rlp[g];
    gc[g] = cosf(a); gs[g] = sinf(a);
  }
  __syncthreads();

  float2 A[16];
  float part[LATENT];
  #pragma unroll
  for (int w = 0; w < LATENT; w++) part[w] = 0.0f;

  int goff = 0;
  for (int c = 0; c < S.ncl; c++) {
    const int q0 = S.cpos[4 * c], q1 = S.cpos[4 * c + 1],
              q2 = S.cpos[4 * c + 2], q3 = S.cpos[4 * c + 3];
    const int m0 = 1 << q0, m1 = 1 << q1, m2 = 1 << q2, m3 = 1 << q3;
    int bi = tid;
    bi = ((bi >> q0) << (q0 + 1)) | (bi & (m0 - 1));
    bi = ((bi >> q1) << (q1 + 1)) | (bi & (m1 - 1));
    bi = ((bi >> q2) << (q2 + 1)) | (bi & (m2 - 1));
    bi = ((bi >> q3) << (q3 + 1)) | (bi & (m3 - 1));
    int idxs[16];
    #pragma unroll
    for (int j = 0; j < 16; j++)
      idxs[j] = bi | ((j & 1) ? m0 : 0) | ((j & 2) ? m1 : 0)
                   | ((j & 4) ? m2 : 0) | ((j & 8) ? m3 : 0);

    if (c == 0) {
      // product-state init straight into registers (14 encoding RX gates fused)
      #pragma unroll
      for (int j = 0; j < 16; j++) {
        int idx = idxs[j];
        float r = 1.0f;
        #pragma unroll
        for (int p = 0; p < N_WIRES; p++)
          r *= ((idx >> p) & 1) ? encs[13 - p] : encc[13 - p];
        int pc = __popc((unsigned)idx) & 3;
        A[j] = make_float2(pc == 0 ? r : (pc == 2 ? -r : 0.0f),
                           pc == 1 ? -r : (pc == 3 ? r : 0.0f));
      }
    } else {
      #pragma unroll
      for (int j = 0; j < 16; j++) A[j] = st[idxs[j]];
    }

    const int ng = S.cng[c];
    for (int e = 0; e < ng; e++) {
      const uint32_t pk = S.gpk[goff + e];
      const int t = pk & 3, la = (pk >> 2) & 3, lt = (pk >> 4) & 3;
      const float cc = gc[pk >> 6], ss = gs[pk >> 6];
      if (t == 0)      { SW1(RXP) }
      else if (t == 1) { SW1(RYP) }
      else if (t == 2) { SW1(RZP) }
      else {
        switch (la * 4 + lt) {
          case 1:  RXP(1,3)  RXP(5,7)   RXP(9,11)  RXP(13,15) break; // c=0,t=1
          case 2:  RXP(1,5)  RXP(3,7)   RXP(9,13)  RXP(11,15) break; // c=0,t=2
          case 3:  RXP(1,9)  RXP(3,11)  RXP(5,13)  RXP(7,15)  break; // c=0,t=3
          case 4:  RXP(2,3)  RXP(6,7)   RXP(10,11) RXP(14,15) break; // c=1,t=0
          case 6:  RXP(2,6)  RXP(3,7)   RXP(10,14) RXP(11,15) break; // c=1,t=2
          case 7:  RXP(2,10) RXP(3,11)  RXP(6,14)  RXP(7,15)  break; // c=1,t=3
          case 8:  RXP(4,5)  RXP(6,7)   RXP(12,13) RXP(14,15) break; // c=2,t=0
          case 9:  RXP(4,6)  RXP(5,7)   RXP(12,14) RXP(13,15) break; // c=2,t=1
          case 11: RXP(4,12) RXP(5,13)  RXP(6,14)  RXP(7,15)  break; // c=2,t=3
          case 12: RXP(8,9)  RXP(10,11) RXP(12,13) RXP(14,15) break; // c=3,t=0
          case 13: RXP(8,10) RXP(9,11)  RXP(12,14) RXP(13,15) break; // c=3,t=1
          default: RXP(8,12) RXP(9,13)  RXP(10,14) RXP(11,15) break; // c=3,t=2
        }
      }
    }
    goff += ng;

    if (c + 1 < S.ncl) {
      #pragma unroll
      for (int j = 0; j < 16; j++) st[idxs[j]] = A[j];
      __syncthreads();
    } else {
      // fuse Z-expectation: accumulate from registers, no final write/read sweep
      #pragma unroll
      for (int j = 0; j < 16; j++) {
        float p2 = A[j].x * A[j].x + A[j].y * A[j].y;
        int idx = idxs[j];
        #pragma unroll
        for (int w = 0; w < LATENT; w++)
          part[w] += ((idx >> (13 - w)) & 1) ? -p2 : p2;
      }
    }
  }

  #pragma unroll
  for (int w = 0; w < LATENT; w++) {
    float v = part[w];
    #pragma unroll
    for (int off = 32; off >= 1; off >>= 1) v += __shfl_down(v, off, 64);
    part[w] = v;
  }
  __syncthreads();               // done with st as state; reuse as reduction scratch
  float* red = (float*)st;
  const int wave = tid >> 6, lane = tid & 63;
  if (lane == 0) {
    #pragma unroll
    for (int w = 0; w < LATENT; w++) red[wave * LATENT + w] = part[w];
  }
  __syncthreads();
  if (tid < LATENT) {
    float v = 0.0f;
    #pragma unroll
    for (int wv = 0; wv < BLOCK / 64; wv++) v += red[wv * LATENT + tid];
    out[b * LATENT + tid] = v;
  }
}

extern "C" void kernel_launch(void* const* d_in, const int* in_sizes, int n_in,
                              void* d_out, int out_size, void* d_ws, size_t ws_size,
                              hipStream_t stream) {
  const float *x   = (const float*)d_in[0];   // [256*14] f32
  const float *rlp = (const float*)d_in[1];   // [50] f32
  float *out = (float*)d_out;                 // [256*8] f32

  Sched S;
  build_sched(S);                             // deterministic host work (capture-time)

  qae_k<<<dim3(BSZ), dim3(BLOCK), 0, stream>>>(x, rlp, out, S);
}

// Round 17
// 106.678 us; speedup vs baseline: 1.3254x; 1.3254x over previous
//
#include <hip/hip_runtime.h>
#include <cstdint>

#define N_WIRES 14
#define N_OPS   50
#define NSTATE  (1 << N_WIRES)   // 16384
#define BSZ     256
#define BLOCK   1024
#define LATENT  8
#define NCLMAX  50

// ---------------- host-side numpy RNG (verified: round-13 PASS, winner mapping m=1) ----------------
namespace nprng {
typedef unsigned __int128 u128;
static const u128 PCG_MULT = (((u128)2549297995355413924ULL) << 64) | 4865540595714422341ULL;

struct PCG64 { u128 state, inc; bool has32; uint32_t buf32; };

static inline uint64_t n64(PCG64 &s) {
  s.state = s.state * PCG_MULT + s.inc;
  uint64_t x = (uint64_t)(s.state >> 64) ^ (uint64_t)s.state;
  unsigned r = (unsigned)(s.state >> 122);
  return (x >> (r & 63)) | (x << ((64 - r) & 63));
}
static inline uint32_t n32(PCG64 &s) {
  if (s.has32) { s.has32 = false; return s.buf32; }
  uint64_t n = n64(s);
  s.has32 = true; s.buf32 = (uint32_t)(n >> 32);
  return (uint32_t)n;
}
static PCG64 seedseq(uint32_t entropy) {
  const uint32_t INIT_A = 0x43b0d7e5u, MULT_A = 0x931e8875u;
  const uint32_t INIT_B = 0x8b51f9ddu, MULT_B = 0x58f38dedu;
  const uint32_t MIX_L = 0xca01f9ddu, MIX_R = 0x4973f715u;
  uint32_t pool[4];
  uint32_t hc = INIT_A;
  auto hashmix = [&](uint32_t v) -> uint32_t {
    v ^= hc; hc *= MULT_A; v *= hc; v ^= v >> 16; return v;
  };
  auto mixf = [&](uint32_t x, uint32_t y) -> uint32_t {
    uint32_t r = x * MIX_L - y * MIX_R;   // multiply-SUBTRACT (the verified fix)
    r ^= r >> 16; return r;
  };
  pool[0] = hashmix(entropy);
  for (int i = 1; i < 4; i++) pool[i] = hashmix(0u);
  for (int s = 0; s < 4; s++)
    for (int d = 0; d < 4; d++)
      if (s != d) pool[d] = mixf(pool[d], hashmix(pool[s]));
  uint32_t w[8];
  uint32_t hb = INIT_B;
  for (int i = 0; i < 8; i++) {
    uint32_t dv = pool[i & 3];
    dv ^= hb; hb *= MULT_B; dv *= hb; dv ^= dv >> 16; w[i] = dv;
  }
  uint64_t v0 = (uint64_t)w[0] | ((uint64_t)w[1] << 32);
  uint64_t v1 = (uint64_t)w[2] | ((uint64_t)w[3] << 32);
  uint64_t v2 = (uint64_t)w[4] | ((uint64_t)w[5] << 32);
  uint64_t v3 = (uint64_t)w[6] | ((uint64_t)w[7] << 32);
  PCG64 r;
  u128 initstate = ((u128)v0 << 64) | v1;
  u128 initseq   = ((u128)v2 << 64) | v3;
  r.inc = (initseq << 1) | 1;
  r.state = 0;
  r.state = r.state * PCG_MULT + r.inc;
  r.state += initstate;
  r.state = r.state * PCG_MULT + r.inc;
  r.has32 = false; r.buf32 = 0;
  return r;
}
static inline uint32_t lem32(PCG64 &r, uint32_t rmax) {
  uint32_t ex = rmax + 1u;
  uint64_t m = (uint64_t)n32(r) * ex;
  uint32_t lo = (uint32_t)m;
  if (lo < ex) {
    uint32_t t = (0xFFFFFFFFu - rmax) % ex;
    while (lo < t) { m = (uint64_t)n32(r) * ex; lo = (uint32_t)m; }
  }
  return (uint32_t)(m >> 32);
}
// winner mapping m=1 (round-14 decode)
static void gatespec(int *gt, int *g0, int *g1) {
  PCG64 r = seedseq(1234u);
  for (int i = 0; i < N_OPS; i++) gt[i] = (int)lem32(r, 3);
  for (int i = 0; i < N_OPS; i++) {
    if (gt[i] < 3) { g0[i] = (int)lem32(r, 13); g1[i] = -1; continue; }
    uint32_t a = lem32(r, 12);
    uint32_t v = lem32(r, 13);
    uint32_t b = (v == a) ? 13u : v;
    uint32_t j = lem32(r, 1);
    if (j == 0) { uint32_t t = a; a = b; b = t; }
    g0[i] = (int)a; g1[i] = (int)b;
  }
}
} // namespace nprng

// ---------------- cluster schedule: 3-wire clusters (8-amp groups) ----------------
struct Sched {
  int ncl;
  int8_t  cpos[NCLMAX * 3];   // 3 sorted-ascending bit positions per cluster
  int8_t  cng[NCLMAX];        // gates per cluster
  uint16_t gpk[N_OPS];        // packed: type | la<<2 | lt<<4 | gidx<<6
};

static void build_sched(Sched &S) {
  int gt[N_OPS], g0[N_OPS], g1[N_OPS];
  nprng::gatespec(gt, g0, g1);

  bool done[N_OPS] = {false};
  int nsched = 0, ncl = 0, gcount = 0;
  while (nsched < N_OPS) {
    int posv[3], posn = 0;
    int clg[N_OPS], ncg = 0;
    bool progress = true;
    while (progress) {
      progress = false;
      for (int i = 0; i < N_OPS; i++) {
        if (done[i]) continue;
        bool avail = true;                       // frontier: no earlier unscheduled gate shares a wire
        for (int j = 0; j < i && avail; j++) {
          if (done[j]) continue;
          if (g0[j] == g0[i] || (g1[i] >= 0 && g0[j] == g1[i])) avail = false;
          else if (g1[j] >= 0 && (g1[j] == g0[i] || (g1[i] >= 0 && g1[j] == g1[i]))) avail = false;
        }
        if (!avail) continue;
        int p0 = 13 - g0[i];
        int p1 = (g1[i] >= 0) ? (13 - g1[i]) : -1;
        bool h0 = false, h1 = (p1 < 0);
        for (int k = 0; k < posn; k++) {
          if (posv[k] == p0) h0 = true;
          if (p1 >= 0 && posv[k] == p1) h1 = true;
        }
        int need = (h0 ? 0 : 1) + ((p1 >= 0 && !h1) ? 1 : 0);
        if (posn + need > 3) continue;
        if (!h0) posv[posn++] = p0;
        if (p1 >= 0 && !h1) posv[posn++] = p1;
        clg[ncg++] = i;
        done[i] = true; nsched++; progress = true;
      }
    }
    for (int p = 0; posn < 3 && p < 14; p++) {
      bool used = false;
      for (int k = 0; k < posn; k++) if (posv[k] == p) used = true;
      if (!used) posv[posn++] = p;
    }
    // sort ascending
    for (int a = 0; a < 2; a++)
      for (int b2 = a + 1; b2 < 3; b2++)
        if (posv[b2] < posv[a]) { int t = posv[a]; posv[a] = posv[b2]; posv[b2] = t; }
    for (int k = 0; k < 3; k++) S.cpos[ncl * 3 + k] = (int8_t)posv[k];
    S.cng[ncl] = (int8_t)ncg;
    for (int e = 0; e < ncg; e++) {
      int i = clg[e];
      int pa = 13 - g0[i], la = 0;
      for (int k = 0; k < 3; k++) if (posv[k] == pa) la = k;
      int lt = 0;
      if (g1[i] >= 0) {
        int pt = 13 - g1[i];
        for (int k = 0; k < 3; k++) if (posv[k] == pt) lt = k;
      }
      S.gpk[gcount++] = (uint16_t)(gt[i] | (la << 2) | (lt << 4) | (i << 6));
    }
    ncl++;
  }
  S.ncl = ncl;
}

// ---------------- device kernel ----------------
// gate macros on Ar/Ai (constant indices -> SROA keeps them in VGPRs)
#define RXP(I0, I1) { float r0 = Ar[I0], q0_ = Ai[I0], r1 = Ar[I1], q1_ = Ai[I1]; \
  Ar[I0] = cc * r0 + ss * q1_; Ai[I0] = cc * q0_ - ss * r1; \
  Ar[I1] = cc * r1 + ss * q0_; Ai[I1] = cc * q1_ - ss * r0; }
#define RYP(I0, I1) { float r0 = Ar[I0], q0_ = Ai[I0], r1 = Ar[I1], q1_ = Ai[I1]; \
  Ar[I0] = cc * r0 - ss * r1; Ai[I0] = cc * q0_ - ss * q1_; \
  Ar[I1] = ss * r0 + cc * r1; Ai[I1] = ss * q0_ + cc * q1_; }
#define RZP(I0, I1) { float r0 = Ar[I0], q0_ = Ai[I0], r1 = Ar[I1], q1_ = Ai[I1]; \
  Ar[I0] = cc * r0 + ss * q0_; Ai[I0] = cc * q0_ - ss * r0; \
  Ar[I1] = cc * r1 - ss * q1_; Ai[I1] = cc * q1_ + ss * r1; }

#define SW1(OP) switch (la) { \
  case 0:  OP(0,1) OP(2,3) OP(4,5) OP(6,7) break; \
  case 1:  OP(0,2) OP(1,3) OP(4,6) OP(5,7) break; \
  default: OP(0,4) OP(1,5) OP(2,6) OP(3,7) break; }

__global__ __launch_bounds__(BLOCK) void qae_k(
    const float* __restrict__ x, const float* __restrict__ rlp,
    float* __restrict__ out, Sched S)
{
  __shared__ float sre[NSTATE];      // SoA: conflict-free lane-consecutive b32 access
  __shared__ float sim_[NSTATE];
  __shared__ float encc[N_WIRES], encs[N_WIRES], gc[N_OPS], gs[N_OPS];
  const int b = blockIdx.x, tid = threadIdx.x;

  if (tid < N_WIRES) {
    float a = 0.5f * x[b * N_WIRES + tid];
    encc[tid] = cosf(a); encs[tid] = sinf(a);
  } else if (tid >= 64 && tid < 64 + N_OPS) {
    int g = tid - 64;
    float a = 0.5f * rlp[g];
    gc[g] = cosf(a); gs[g] = sinf(a);
  }
  __syncthreads();

  float pr[LATENT];
  #pragma unroll
  for (int w = 0; w < LATENT; w++) pr[w] = 0.0f;

  int goff = 0;
  const int ncl = S.ncl;
  for (int c = 0; c < ncl; c++) {
    const int q0 = S.cpos[3 * c], q1 = S.cpos[3 * c + 1], q2 = S.cpos[3 * c + 2];
    const int m0 = 1 << q0, m1 = 1 << q1, m2 = 1 << q2;
    const int ng = S.cng[c];

    #pragma unroll 1                 // keep the two 8-amp groups SEQUENTIAL (register cap!)
    for (int grp = 0; grp < 2; ++grp) {
      int g = tid + (grp << 10);
      int bi = g;
      bi = ((bi >> q0) << (q0 + 1)) | (bi & (m0 - 1));
      bi = ((bi >> q1) << (q1 + 1)) | (bi & (m1 - 1));
      bi = ((bi >> q2) << (q2 + 1)) | (bi & (m2 - 1));
      const int ids[8] = { bi,            bi | m0,        bi | m1,        bi | (m0 | m1),
                           bi | m2,       bi | (m2 | m0), bi | (m2 | m1), bi | (m2 | m1 | m0) };
      float Ar[8], Ai[8];

      if (c == 0) {
        // product-state init straight into registers (14 encoding RX gates fused)
        #pragma unroll
        for (int j = 0; j < 8; j++) {
          int idx = ids[j];
          float r = 1.0f;
          #pragma unroll
          for (int p = 0; p < N_WIRES; p++)
            r *= ((idx >> p) & 1) ? encs[13 - p] : encc[13 - p];
          int pc = __popc((unsigned)idx) & 3;
          Ar[j] = (pc == 0) ? r : ((pc == 2) ? -r : 0.0f);
          Ai[j] = (pc == 1) ? -r : ((pc == 3) ? r : 0.0f);
        }
      } else {
        #pragma unroll
        for (int j = 0; j < 8; j++) { Ar[j] = sre[ids[j]]; Ai[j] = sim_[ids[j]]; }
      }

      for (int e = 0; e < ng; e++) {
        const uint32_t pk = S.gpk[goff + e];
        const int t = pk & 3, la = (pk >> 2) & 3, lt = (pk >> 4) & 3;
        const float cc = gc[pk >> 6], ss = gs[pk >> 6];
        if (t == 0)      { SW1(RXP) }
        else if (t == 1) { SW1(RYP) }
        else if (t == 2) { SW1(RZP) }
        else {
          switch (la * 3 + lt) {
            case 1:  RXP(1,3) RXP(5,7) break;   // ctrl slot0, tgt slot1
            case 2:  RXP(1,5) RXP(3,7) break;   // ctrl slot0, tgt slot2
            case 3:  RXP(2,3) RXP(6,7) break;   // ctrl slot1, tgt slot0
            case 5:  RXP(2,6) RXP(3,7) break;   // ctrl slot1, tgt slot2
            case 6:  RXP(4,5) RXP(6,7) break;   // ctrl slot2, tgt slot0
            default: RXP(4,6) RXP(5,7) break;   // ctrl slot2, tgt slot1
          }
        }
      }

      if (c + 1 < ncl) {
        #pragma unroll
        for (int j = 0; j < 8; j++) { sre[ids[j]] = Ar[j]; sim_[ids[j]] = Ai[j]; }
      } else {
        // fused Z-expectation from registers
        #pragma unroll
        for (int j = 0; j < 8; j++) {
          float p2 = Ar[j] * Ar[j] + Ai[j] * Ai[j];
          int idx = ids[j];
          #pragma unroll
          for (int w = 0; w < LATENT; w++)
            pr[w] += ((idx >> (13 - w)) & 1) ? -p2 : p2;
        }
      }
    }
    goff += ng;
    if (c + 1 < ncl) __syncthreads();
  }

  #pragma unroll
  for (int w = 0; w < LATENT; w++) {
    float v = pr[w];
    #pragma unroll
    for (int off = 32; off >= 1; off >>= 1) v += __shfl_down(v, off, 64);
    pr[w] = v;
  }
  __syncthreads();               // done with LDS state; reuse as reduction scratch
  float* red = sre;
  const int wave = tid >> 6, lane = tid & 63;
  if (lane == 0) {
    #pragma unroll
    for (int w = 0; w < LATENT; w++) red[wave * LATENT + w] = pr[w];
  }
  __syncthreads();
  if (tid < LATENT) {
    float v = 0.0f;
    #pragma unroll
    for (int wv = 0; wv < BLOCK / 64; wv++) v += red[wv * LATENT + tid];
    out[b * LATENT + tid] = v;
  }
}

extern "C" void kernel_launch(void* const* d_in, const int* in_sizes, int n_in,
                              void* d_out, int out_size, void* d_ws, size_t ws_size,
                              hipStream_t stream) {
  const float *x   = (const float*)d_in[0];   // [256*14] f32
  const float *rlp = (const float*)d_in[1];   // [50] f32
  float *out = (float*)d_out;                 // [256*8] f32

  Sched S;
  build_sched(S);                             // deterministic host work (capture-time)

  qae_k<<<dim3(BSZ), dim3(BLOCK), 0, stream>>>(x, rlp, out, S);
}

// Round 18
// 82.726 us; speedup vs baseline: 1.7092x; 1.2895x over previous
//
#include <hip/hip_runtime.h>
#include <cstdint>

#define N_WIRES 14
#define N_OPS   50
#define NSTATE  (1 << N_WIRES)   // 16384
#define BSZ     256
#define BLOCK   1024
#define LATENT  8
#define NCLMAX  50
#define LDSN    (NSTATE + (NSTATE >> 5))   // +1-per-32 padded
#define PHYS(i) ((i) + ((i) >> 5))

// ---------------- host-side numpy RNG (verified: round-13 PASS, winner mapping m=1) ----------------
namespace nprng {
typedef unsigned __int128 u128;
static const u128 PCG_MULT = (((u128)2549297995355413924ULL) << 64) | 4865540595714422341ULL;

struct PCG64 { u128 state, inc; bool has32; uint32_t buf32; };

static inline uint64_t n64(PCG64 &s) {
  s.state = s.state * PCG_MULT + s.inc;
  uint64_t x = (uint64_t)(s.state >> 64) ^ (uint64_t)s.state;
  unsigned r = (unsigned)(s.state >> 122);
  return (x >> (r & 63)) | (x << ((64 - r) & 63));
}
static inline uint32_t n32(PCG64 &s) {
  if (s.has32) { s.has32 = false; return s.buf32; }
  uint64_t n = n64(s);
  s.has32 = true; s.buf32 = (uint32_t)(n >> 32);
  return (uint32_t)n;
}
static PCG64 seedseq(uint32_t entropy) {
  const uint32_t INIT_A = 0x43b0d7e5u, MULT_A = 0x931e8875u;
  const uint32_t INIT_B = 0x8b51f9ddu, MULT_B = 0x58f38dedu;
  const uint32_t MIX_L = 0xca01f9ddu, MIX_R = 0x4973f715u;
  uint32_t pool[4];
  uint32_t hc = INIT_A;
  auto hashmix = [&](uint32_t v) -> uint32_t {
    v ^= hc; hc *= MULT_A; v *= hc; v ^= v >> 16; return v;
  };
  auto mixf = [&](uint32_t x, uint32_t y) -> uint32_t {
    uint32_t r = x * MIX_L - y * MIX_R;   // multiply-SUBTRACT (the verified fix)
    r ^= r >> 16; return r;
  };
  pool[0] = hashmix(entropy);
  for (int i = 1; i < 4; i++) pool[i] = hashmix(0u);
  for (int s = 0; s < 4; s++)
    for (int d = 0; d < 4; d++)
      if (s != d) pool[d] = mixf(pool[d], hashmix(pool[s]));
  uint32_t w[8];
  uint32_t hb = INIT_B;
  for (int i = 0; i < 8; i++) {
    uint32_t dv = pool[i & 3];
    dv ^= hb; hb *= MULT_B; dv *= hb; dv ^= dv >> 16; w[i] = dv;
  }
  uint64_t v0 = (uint64_t)w[0] | ((uint64_t)w[1] << 32);
  uint64_t v1 = (uint64_t)w[2] | ((uint64_t)w[3] << 32);
  uint64_t v2 = (uint64_t)w[4] | ((uint64_t)w[5] << 32);
  uint64_t v3 = (uint64_t)w[6] | ((uint64_t)w[7] << 32);
  PCG64 r;
  u128 initstate = ((u128)v0 << 64) | v1;
  u128 initseq   = ((u128)v2 << 64) | v3;
  r.inc = (initseq << 1) | 1;
  r.state = 0;
  r.state = r.state * PCG_MULT + r.inc;
  r.state += initstate;
  r.state = r.state * PCG_MULT + r.inc;
  r.has32 = false; r.buf32 = 0;
  return r;
}
static inline uint32_t lem32(PCG64 &r, uint32_t rmax) {
  uint32_t ex = rmax + 1u;
  uint64_t m = (uint64_t)n32(r) * ex;
  uint32_t lo = (uint32_t)m;
  if (lo < ex) {
    uint32_t t = (0xFFFFFFFFu - rmax) % ex;
    while (lo < t) { m = (uint64_t)n32(r) * ex; lo = (uint32_t)m; }
  }
  return (uint32_t)(m >> 32);
}
// winner mapping m=1 (round-14 decode)
static void gatespec(int *gt, int *g0, int *g1) {
  PCG64 r = seedseq(1234u);
  for (int i = 0; i < N_OPS; i++) gt[i] = (int)lem32(r, 3);
  for (int i = 0; i < N_OPS; i++) {
    if (gt[i] < 3) { g0[i] = (int)lem32(r, 13); g1[i] = -1; continue; }
    uint32_t a = lem32(r, 12);
    uint32_t v = lem32(r, 13);
    uint32_t b = (v == a) ? 13u : v;
    uint32_t j = lem32(r, 1);
    if (j == 0) { uint32_t t = a; a = b; b = t; }
    g0[i] = (int)a; g1[i] = (int)b;
  }
}
} // namespace nprng

// ---------------- cluster schedule: 3-wire clusters (8-amp groups) ----------------
struct Sched {
  int ncl;
  int8_t  cpos[NCLMAX * 3];
  int8_t  cng[NCLMAX];
  uint16_t gpk[N_OPS];        // packed: type | la<<2 | lt<<4 | gidx<<6
};

static void build_sched(Sched &S) {
  int gt[N_OPS], g0[N_OPS], g1[N_OPS];
  nprng::gatespec(gt, g0, g1);

  bool done[N_OPS] = {false};
  int nsched = 0, ncl = 0, gcount = 0;
  while (nsched < N_OPS) {
    int posv[3], posn = 0;
    int clg[N_OPS], ncg = 0;
    bool progress = true;
    while (progress) {
      progress = false;
      for (int i = 0; i < N_OPS; i++) {
        if (done[i]) continue;
        bool avail = true;                 // frontier: no earlier unscheduled gate shares a wire
        for (int j = 0; j < i && avail; j++) {
          if (done[j]) continue;
          if (g0[j] == g0[i] || (g1[i] >= 0 && g0[j] == g1[i])) avail = false;
          else if (g1[j] >= 0 && (g1[j] == g0[i] || (g1[i] >= 0 && g1[j] == g1[i]))) avail = false;
        }
        if (!avail) continue;
        int p0 = 13 - g0[i];
        int p1 = (g1[i] >= 0) ? (13 - g1[i]) : -1;
        bool h0 = false, h1 = (p1 < 0);
        for (int k = 0; k < posn; k++) {
          if (posv[k] == p0) h0 = true;
          if (p1 >= 0 && posv[k] == p1) h1 = true;
        }
        int need = (h0 ? 0 : 1) + ((p1 >= 0 && !h1) ? 1 : 0);
        if (posn + need > 3) continue;
        if (!h0) posv[posn++] = p0;
        if (p1 >= 0 && !h1) posv[posn++] = p1;
        clg[ncg++] = i;
        done[i] = true; nsched++; progress = true;
      }
    }
    for (int p = 0; posn < 3 && p < 14; p++) {
      bool used = false;
      for (int k = 0; k < posn; k++) if (posv[k] == p) used = true;
      if (!used) posv[posn++] = p;
    }
    for (int a = 0; a < 2; a++)
      for (int b2 = a + 1; b2 < 3; b2++)
        if (posv[b2] < posv[a]) { int t = posv[a]; posv[a] = posv[b2]; posv[b2] = t; }
    for (int k = 0; k < 3; k++) S.cpos[ncl * 3 + k] = (int8_t)posv[k];
    S.cng[ncl] = (int8_t)ncg;
    for (int e = 0; e < ncg; e++) {
      int i = clg[e];
      int pa = 13 - g0[i], la = 0;
      for (int k = 0; k < 3; k++) if (posv[k] == pa) la = k;
      int lt = 0;
      if (g1[i] >= 0) {
        int pt = 13 - g1[i];
        for (int k = 0; k < 3; k++) if (posv[k] == pt) lt = k;
      }
      S.gpk[gcount++] = (uint16_t)(gt[i] | (la << 2) | (lt << 4) | (i << 6));
    }
    ncl++;
  }
  S.ncl = ncl;
}

// ---------------- device kernel ----------------
#define RXP(I0, I1) { float r0 = Ar[I0], q0_ = Ai[I0], r1 = Ar[I1], q1_ = Ai[I1]; \
  Ar[I0] = cc * r0 + ss * q1_; Ai[I0] = cc * q0_ - ss * r1; \
  Ar[I1] = cc * r1 + ss * q0_; Ai[I1] = cc * q1_ - ss * r0; }
#define RYP(I0, I1) { float r0 = Ar[I0], q0_ = Ai[I0], r1 = Ar[I1], q1_ = Ai[I1]; \
  Ar[I0] = cc * r0 - ss * r1; Ai[I0] = cc * q0_ - ss * q1_; \
  Ar[I1] = ss * r0 + cc * r1; Ai[I1] = ss * q0_ + cc * q1_; }
#define RZP(I0, I1) { float r0 = Ar[I0], q0_ = Ai[I0], r1 = Ar[I1], q1_ = Ai[I1]; \
  Ar[I0] = cc * r0 + ss * q0_; Ai[I0] = cc * q0_ - ss * r0; \
  Ar[I1] = cc * r1 - ss * q1_; Ai[I1] = cc * q1_ + ss * r1; }

#define SW1(OP) switch (la) { \
  case 0:  OP(0,1) OP(2,3) OP(4,5) OP(6,7) break; \
  case 1:  OP(0,2) OP(1,3) OP(4,6) OP(5,7) break; \
  default: OP(0,4) OP(1,5) OP(2,6) OP(3,7) break; }

__global__ __launch_bounds__(BLOCK) void qae_k(
    const float* __restrict__ x, const float* __restrict__ rlp,
    float* __restrict__ out, Sched S)
{
  __shared__ float sre[LDSN];
  __shared__ float sim_[LDSN];
  __shared__ float encc[N_WIRES], encs[N_WIRES], gc[N_OPS], gs[N_OPS];
  const int b = blockIdx.x, tid = threadIdx.x;

  if (tid < N_WIRES) {
    float a = 0.5f * x[b * N_WIRES + tid];
    encc[tid] = cosf(a); encs[tid] = sinf(a);
  } else if (tid >= 64 && tid < 64 + N_OPS) {
    int g = tid - 64;
    float a = 0.5f * rlp[g];
    gc[g] = cosf(a); gs[g] = sinf(a);
  }
  __syncthreads();

  // --- init sweep (strided, conflict-free), fuses the 14 encoding RX gates ---
  #pragma unroll 1
  for (int k = tid; k < NSTATE; k += BLOCK) {
    float r = 1.0f;
    #pragma unroll
    for (int p = 0; p < N_WIRES; p++)
      r *= ((k >> p) & 1) ? encs[13 - p] : encc[13 - p];
    int pc = __popc((unsigned)k) & 3;
    sre[PHYS(k)]  = (pc == 0) ? r : ((pc == 2) ? -r : 0.0f);
    sim_[PHYS(k)] = (pc == 1) ? -r : ((pc == 3) ? r : 0.0f);
  }
  __syncthreads();

  float pr[LATENT];
  #pragma unroll
  for (int w = 0; w < LATENT; w++) pr[w] = 0.0f;

  int goff = 0;
  const int ncl = S.ncl;
  for (int c = 0; c < ncl; c++) {
    const int q0 = S.cpos[3 * c], q1 = S.cpos[3 * c + 1], q2 = S.cpos[3 * c + 2];
    const int m0 = 1 << q0, m1 = 1 << q1, m2 = 1 << q2;
    const int ng = S.cng[c];

    #pragma unroll 1                 // keep the two 8-amp groups SEQUENTIAL (register cap)
    for (int grp = 0; grp < 2; ++grp) {
      int g = tid + (grp << 10);
      int bi = g;
      bi = ((bi >> q0) << (q0 + 1)) | (bi & (m0 - 1));
      bi = ((bi >> q1) << (q1 + 1)) | (bi & (m1 - 1));
      bi = ((bi >> q2) << (q2 + 1)) | (bi & (m2 - 1));

      float Ar[8], Ai[8];
      Ar[0] = sre[PHYS(bi)];                 Ai[0] = sim_[PHYS(bi)];
      Ar[1] = sre[PHYS(bi | m0)];            Ai[1] = sim_[PHYS(bi | m0)];
      Ar[2] = sre[PHYS(bi | m1)];            Ai[2] = sim_[PHYS(bi | m1)];
      Ar[3] = sre[PHYS(bi | m0 | m1)];       Ai[3] = sim_[PHYS(bi | m0 | m1)];
      Ar[4] = sre[PHYS(bi | m2)];            Ai[4] = sim_[PHYS(bi | m2)];
      Ar[5] = sre[PHYS(bi | m0 | m2)];       Ai[5] = sim_[PHYS(bi | m0 | m2)];
      Ar[6] = sre[PHYS(bi | m1 | m2)];       Ai[6] = sim_[PHYS(bi | m1 | m2)];
      Ar[7] = sre[PHYS(bi | m0 | m1 | m2)];  Ai[7] = sim_[PHYS(bi | m0 | m1 | m2)];

      for (int e = 0; e < ng; e++) {
        const uint32_t pk = S.gpk[goff + e];
        const int t = pk & 3, la = (pk >> 2) & 3, lt = (pk >> 4) & 3;
        const float cc = gc[pk >> 6], ss = gs[pk >> 6];
        if (t == 0)      { SW1(RXP) }
        else if (t == 1) { SW1(RYP) }
        else if (t == 2) { SW1(RZP) }
        else {
          switch (la * 3 + lt) {
            case 1:  RXP(1,3) RXP(5,7) break;   // ctrl slot0, tgt slot1
            case 2:  RXP(1,5) RXP(3,7) break;   // ctrl slot0, tgt slot2
            case 3:  RXP(2,3) RXP(6,7) break;   // ctrl slot1, tgt slot0
            case 5:  RXP(2,6) RXP(3,7) break;   // ctrl slot1, tgt slot2
            case 6:  RXP(4,5) RXP(6,7) break;   // ctrl slot2, tgt slot0
            default: RXP(4,6) RXP(5,7) break;   // ctrl slot2, tgt slot1
          }
        }
      }

      if (c + 1 < ncl) {
        sre[PHYS(bi)]                = Ar[0];  sim_[PHYS(bi)]                = Ai[0];
        sre[PHYS(bi | m0)]           = Ar[1];  sim_[PHYS(bi | m0)]           = Ai[1];
        sre[PHYS(bi | m1)]           = Ar[2];  sim_[PHYS(bi | m1)]           = Ai[2];
        sre[PHYS(bi | m0 | m1)]      = Ar[3];  sim_[PHYS(bi | m0 | m1)]      = Ai[3];
        sre[PHYS(bi | m2)]           = Ar[4];  sim_[PHYS(bi | m2)]           = Ai[4];
        sre[PHYS(bi | m0 | m2)]      = Ar[5];  sim_[PHYS(bi | m0 | m2)]      = Ai[5];
        sre[PHYS(bi | m1 | m2)]      = Ar[6];  sim_[PHYS(bi | m1 | m2)]      = Ai[6];
        sre[PHYS(bi | m0 | m1 | m2)] = Ar[7];  sim_[PHYS(bi | m0 | m1 | m2)] = Ai[7];
      } else {
        // fused Z-expectation from registers
        #pragma unroll
        for (int j = 0; j < 8; j++) {
          float p2 = Ar[j] * Ar[j] + Ai[j] * Ai[j];
          int idx = bi | ((j & 1) ? m0 : 0) | ((j & 2) ? m1 : 0) | ((j & 4) ? m2 : 0);
          #pragma unroll
          for (int w = 0; w < LATENT; w++)
            pr[w] += ((idx >> (13 - w)) & 1) ? -p2 : p2;
        }
      }
    }
    goff += ng;
    if (c + 1 < ncl) __syncthreads();
  }

  #pragma unroll
  for (int w = 0; w < LATENT; w++) {
    float v = pr[w];
    #pragma unroll
    for (int off = 32; off >= 1; off >>= 1) v += __shfl_down(v, off, 64);
    pr[w] = v;
  }
  __syncthreads();               // done with LDS state; reuse as reduction scratch
  float* red = sre;
  const int wave = tid >> 6, lane = tid & 63;
  if (lane == 0) {
    #pragma unroll
    for (int w = 0; w < LATENT; w++) red[wave * LATENT + w] = pr[w];
  }
  __syncthreads();
  if (tid < LATENT) {
    float v = 0.0f;
    #pragma unroll
    for (int wv = 0; wv < BLOCK / 64; wv++) v += red[wv * LATENT + tid];
    out[b * LATENT + tid] = v;
  }
}

extern "C" void kernel_launch(void* const* d_in, const int* in_sizes, int n_in,
                              void* d_out, int out_size, void* d_ws, size_t ws_size,
                              hipStream_t stream) {
  const float *x   = (const float*)d_in[0];   // [256*14] f32
  const float *rlp = (const float*)d_in[1];   // [50] f32
  float *out = (float*)d_out;                 // [256*8] f32

  Sched S;
  build_sched(S);                             // deterministic host work (capture-time)

  qae_k<<<dim3(BSZ), dim3(BLOCK), 0, stream>>>(x, rlp, out, S);
}

// Round 19
// 81.785 us; speedup vs baseline: 1.7288x; 1.0115x over previous
//
#include <hip/hip_runtime.h>
#include <cstdint>

#define N_WIRES 14
#define N_OPS   50
#define NSTATE  (1 << N_WIRES)   // 16384
#define BSZ     256
#define BLOCK   1024
#define LATENT  8
#define NCLMAX  50
#define LDSN    (NSTATE + (NSTATE >> 5))   // +1-per-32 padded
#define PHYS(i) ((i) + ((i) >> 5))

// ---------------- host-side numpy RNG (verified: round-13 PASS, winner mapping m=1) ----------------
namespace nprng {
typedef unsigned __int128 u128;
static const u128 PCG_MULT = (((u128)2549297995355413924ULL) << 64) | 4865540595714422341ULL;

struct PCG64 { u128 state, inc; bool has32; uint32_t buf32; };

static inline uint64_t n64(PCG64 &s) {
  s.state = s.state * PCG_MULT + s.inc;
  uint64_t x = (uint64_t)(s.state >> 64) ^ (uint64_t)s.state;
  unsigned r = (unsigned)(s.state >> 122);
  return (x >> (r & 63)) | (x << ((64 - r) & 63));
}
static inline uint32_t n32(PCG64 &s) {
  if (s.has32) { s.has32 = false; return s.buf32; }
  uint64_t n = n64(s);
  s.has32 = true; s.buf32 = (uint32_t)(n >> 32);
  return (uint32_t)n;
}
static PCG64 seedseq(uint32_t entropy) {
  const uint32_t INIT_A = 0x43b0d7e5u, MULT_A = 0x931e8875u;
  const uint32_t INIT_B = 0x8b51f9ddu, MULT_B = 0x58f38dedu;
  const uint32_t MIX_L = 0xca01f9ddu, MIX_R = 0x4973f715u;
  uint32_t pool[4];
  uint32_t hc = INIT_A;
  auto hashmix = [&](uint32_t v) -> uint32_t {
    v ^= hc; hc *= MULT_A; v *= hc; v ^= v >> 16; return v;
  };
  auto mixf = [&](uint32_t x, uint32_t y) -> uint32_t {
    uint32_t r = x * MIX_L - y * MIX_R;   // multiply-SUBTRACT (the verified fix)
    r ^= r >> 16; return r;
  };
  pool[0] = hashmix(entropy);
  for (int i = 1; i < 4; i++) pool[i] = hashmix(0u);
  for (int s = 0; s < 4; s++)
    for (int d = 0; d < 4; d++)
      if (s != d) pool[d] = mixf(pool[d], hashmix(pool[s]));
  uint32_t w[8];
  uint32_t hb = INIT_B;
  for (int i = 0; i < 8; i++) {
    uint32_t dv = pool[i & 3];
    dv ^= hb; hb *= MULT_B; dv *= hb; dv ^= dv >> 16; w[i] = dv;
  }
  uint64_t v0 = (uint64_t)w[0] | ((uint64_t)w[1] << 32);
  uint64_t v1 = (uint64_t)w[2] | ((uint64_t)w[3] << 32);
  uint64_t v2 = (uint64_t)w[4] | ((uint64_t)w[5] << 32);
  uint64_t v3 = (uint64_t)w[6] | ((uint64_t)w[7] << 32);
  PCG64 r;
  u128 initstate = ((u128)v0 << 64) | v1;
  u128 initseq   = ((u128)v2 << 64) | v3;
  r.inc = (initseq << 1) | 1;
  r.state = 0;
  r.state = r.state * PCG_MULT + r.inc;
  r.state += initstate;
  r.state = r.state * PCG_MULT + r.inc;
  r.has32 = false; r.buf32 = 0;
  return r;
}
static inline uint32_t lem32(PCG64 &r, uint32_t rmax) {
  uint32_t ex = rmax + 1u;
  uint64_t m = (uint64_t)n32(r) * ex;
  uint32_t lo = (uint32_t)m;
  if (lo < ex) {
    uint32_t t = (0xFFFFFFFFu - rmax) % ex;
    while (lo < t) { m = (uint64_t)n32(r) * ex; lo = (uint32_t)m; }
  }
  return (uint32_t)(m >> 32);
}
// winner mapping m=1 (round-14 decode)
static void gatespec(int *gt, int *g0, int *g1) {
  PCG64 r = seedseq(1234u);
  for (int i = 0; i < N_OPS; i++) gt[i] = (int)lem32(r, 3);
  for (int i = 0; i < N_OPS; i++) {
    if (gt[i] < 3) { g0[i] = (int)lem32(r, 13); g1[i] = -1; continue; }
    uint32_t a = lem32(r, 12);
    uint32_t v = lem32(r, 13);
    uint32_t b = (v == a) ? 13u : v;
    uint32_t j = lem32(r, 1);
    if (j == 0) { uint32_t t = a; a = b; b = t; }
    g0[i] = (int)a; g1[i] = (int)b;
  }
}
} // namespace nprng

// ---------------- cluster schedule: 3-wire clusters (8-amp groups) ----------------
struct Sched {
  int ncl;
  int8_t  cpos[NCLMAX * 3];
  int8_t  cng[NCLMAX];
  uint16_t gpk[N_OPS];        // packed: type | la<<2 | lt<<4 | gidx<<6
};

static void build_sched(Sched &S) {
  int gt[N_OPS], g0[N_OPS], g1[N_OPS];
  nprng::gatespec(gt, g0, g1);

  bool done[N_OPS] = {false};
  int nsched = 0, ncl = 0, gcount = 0;
  while (nsched < N_OPS) {
    int posv[3], posn = 0;
    int clg[N_OPS], ncg = 0;
    bool progress = true;
    while (progress) {
      progress = false;
      for (int i = 0; i < N_OPS; i++) {
        if (done[i]) continue;
        bool avail = true;                 // frontier: no earlier unscheduled gate shares a wire
        for (int j = 0; j < i && avail; j++) {
          if (done[j]) continue;
          if (g0[j] == g0[i] || (g1[i] >= 0 && g0[j] == g1[i])) avail = false;
          else if (g1[j] >= 0 && (g1[j] == g0[i] || (g1[i] >= 0 && g1[j] == g1[i]))) avail = false;
        }
        if (!avail) continue;
        int p0 = 13 - g0[i];
        int p1 = (g1[i] >= 0) ? (13 - g1[i]) : -1;
        bool h0 = false, h1 = (p1 < 0);
        for (int k = 0; k < posn; k++) {
          if (posv[k] == p0) h0 = true;
          if (p1 >= 0 && posv[k] == p1) h1 = true;
        }
        int need = (h0 ? 0 : 1) + ((p1 >= 0 && !h1) ? 1 : 0);
        if (posn + need > 3) continue;
        if (!h0) posv[posn++] = p0;
        if (p1 >= 0 && !h1) posv[posn++] = p1;
        clg[ncg++] = i;
        done[i] = true; nsched++; progress = true;
      }
    }
    for (int p = 0; posn < 3 && p < 14; p++) {
      bool used = false;
      for (int k = 0; k < posn; k++) if (posv[k] == p) used = true;
      if (!used) posv[posn++] = p;
    }
    for (int a = 0; a < 2; a++)
      for (int b2 = a + 1; b2 < 3; b2++)
        if (posv[b2] < posv[a]) { int t = posv[a]; posv[a] = posv[b2]; posv[b2] = t; }
    for (int k = 0; k < 3; k++) S.cpos[ncl * 3 + k] = (int8_t)posv[k];
    S.cng[ncl] = (int8_t)ncg;
    for (int e = 0; e < ncg; e++) {
      int i = clg[e];
      int pa = 13 - g0[i], la = 0;
      for (int k = 0; k < 3; k++) if (posv[k] == pa) la = k;
      int lt = 0;
      if (g1[i] >= 0) {
        int pt = 13 - g1[i];
        for (int k = 0; k < 3; k++) if (posv[k] == pt) lt = k;
      }
      S.gpk[gcount++] = (uint16_t)(gt[i] | (la << 2) | (lt << 4) | (i << 6));
    }
    ncl++;
  }
  S.ncl = ncl;
}

// ---------------- device kernel ----------------
#define RXP(I0, I1) { float r0 = Ar[I0], q0_ = Ai[I0], r1 = Ar[I1], q1_ = Ai[I1]; \
  Ar[I0] = cc * r0 + ss * q1_; Ai[I0] = cc * q0_ - ss * r1; \
  Ar[I1] = cc * r1 + ss * q0_; Ai[I1] = cc * q1_ - ss * r0; }
#define RYP(I0, I1) { float r0 = Ar[I0], q0_ = Ai[I0], r1 = Ar[I1], q1_ = Ai[I1]; \
  Ar[I0] = cc * r0 - ss * r1; Ai[I0] = cc * q0_ - ss * q1_; \
  Ar[I1] = ss * r0 + cc * r1; Ai[I1] = ss * q0_ + cc * q1_; }
#define RZP(I0, I1) { float r0 = Ar[I0], q0_ = Ai[I0], r1 = Ar[I1], q1_ = Ai[I1]; \
  Ar[I0] = cc * r0 + ss * q0_; Ai[I0] = cc * q0_ - ss * r0; \
  Ar[I1] = cc * r1 - ss * q1_; Ai[I1] = cc * q1_ + ss * r1; }

#define SW1(OP) switch (la) { \
  case 0:  OP(0,1) OP(2,3) OP(4,5) OP(6,7) break; \
  case 1:  OP(0,2) OP(1,3) OP(4,6) OP(5,7) break; \
  default: OP(0,4) OP(1,5) OP(2,6) OP(3,7) break; }

// gate application on the 8-amp register tile (shared by hot loop and peeled tail)
#define APPLY_GATES() \
  for (int e = 0; e < ng; e++) { \
    const int pk = lpk[goff + e]; \
    const int t = pk & 3, la = (pk >> 2) & 3, lt = (pk >> 4) & 3; \
    const float2 cs = coef[pk >> 6]; \
    const float cc = cs.x, ss = cs.y; \
    if (t == 0)      { SW1(RXP) } \
    else if (t == 1) { SW1(RYP) } \
    else if (t == 2) { SW1(RZP) } \
    else { \
      switch (la * 3 + lt) { \
        case 1:  RXP(1,3) RXP(5,7) break; \
        case 2:  RXP(1,5) RXP(3,7) break; \
        case 3:  RXP(2,3) RXP(6,7) break; \
        case 5:  RXP(2,6) RXP(3,7) break; \
        case 6:  RXP(4,5) RXP(6,7) break; \
        default: RXP(4,6) RXP(5,7) break; \
      } \
    } \
  }

__global__ __launch_bounds__(BLOCK) void qae_k(
    const float* __restrict__ x, const float* __restrict__ rlp,
    float* __restrict__ out, Sched S)
{
  __shared__ float sre[LDSN];
  __shared__ float sim_[LDSN];
  __shared__ float encc[N_WIRES], encs[N_WIRES];
  __shared__ float2 coef[N_OPS];       // (cos, sin) per gate — one b64 broadcast read
  __shared__ int lpk[N_OPS];           // schedule in LDS (kills kernarg->scratch dynamic idx)
  __shared__ int lcl[NCLMAX];          // q0 | q1<<8 | q2<<16 | ng<<24
  __shared__ int lncl;
  const int b = blockIdx.x, tid = threadIdx.x;

  if (tid < N_WIRES) {
    float a = 0.5f * x[b * N_WIRES + tid];
    encc[tid] = cosf(a); encs[tid] = sinf(a);
  } else if (tid >= 64 && tid < 64 + N_OPS) {
    int g = tid - 64;
    float a = 0.5f * rlp[g];
    coef[g] = make_float2(cosf(a), sinf(a));
  } else if (tid >= 128 && tid < 128 + N_OPS) {
    int g = tid - 128;
    lpk[g] = (int)S.gpk[g];            // one-time scratch read, then LDS forever
  } else if (tid >= 192 && tid < 192 + NCLMAX) {
    int c = tid - 192;
    lcl[c] = (int)S.cpos[3 * c] | ((int)S.cpos[3 * c + 1] << 8)
           | ((int)S.cpos[3 * c + 2] << 16) | ((int)S.cng[c] << 24);
  } else if (tid == 63) {
    lncl = S.ncl;
  }
  __syncthreads();

  // --- init sweep (strided, conflict-free), fuses the 14 encoding RX gates ---
  #pragma unroll 1
  for (int k = tid; k < NSTATE; k += BLOCK) {
    float r = 1.0f;
    #pragma unroll
    for (int p = 0; p < N_WIRES; p++)
      r *= ((k >> p) & 1) ? encs[13 - p] : encc[13 - p];
    int pc = __popc((unsigned)k) & 3;
    sre[PHYS(k)]  = (pc == 0) ? r : ((pc == 2) ? -r : 0.0f);
    sim_[PHYS(k)] = (pc == 1) ? -r : ((pc == 3) ? r : 0.0f);
  }
  __syncthreads();

  float pr[LATENT];
  #pragma unroll
  for (int w = 0; w < LATENT; w++) pr[w] = 0.0f;

  const int ncl = lncl;
  int goff = 0;

  // --- hot loop: all clusters except the last (always store back) ---
  for (int c = 0; c < ncl - 1; c++) {
    const int ci = lcl[c];
    const int q0 = ci & 255, q1 = (ci >> 8) & 255, q2 = (ci >> 16) & 255;
    const int ng = (ci >> 24) & 255;
    const int m0 = 1 << q0, m1 = 1 << q1, m2 = 1 << q2;

    #pragma unroll 1
    for (int grp = 0; grp < 2; ++grp) {
      int g = tid + (grp << 10);
      int bi = g;
      bi = ((bi >> q0) << (q0 + 1)) | (bi & (m0 - 1));
      bi = ((bi >> q1) << (q1 + 1)) | (bi & (m1 - 1));
      bi = ((bi >> q2) << (q2 + 1)) | (bi & (m2 - 1));

      float Ar[8], Ai[8];
      Ar[0] = sre[PHYS(bi)];                 Ai[0] = sim_[PHYS(bi)];
      Ar[1] = sre[PHYS(bi | m0)];            Ai[1] = sim_[PHYS(bi | m0)];
      Ar[2] = sre[PHYS(bi | m1)];            Ai[2] = sim_[PHYS(bi | m1)];
      Ar[3] = sre[PHYS(bi | m0 | m1)];       Ai[3] = sim_[PHYS(bi | m0 | m1)];
      Ar[4] = sre[PHYS(bi | m2)];            Ai[4] = sim_[PHYS(bi | m2)];
      Ar[5] = sre[PHYS(bi | m0 | m2)];       Ai[5] = sim_[PHYS(bi | m0 | m2)];
      Ar[6] = sre[PHYS(bi | m1 | m2)];       Ai[6] = sim_[PHYS(bi | m1 | m2)];
      Ar[7] = sre[PHYS(bi | m0 | m1 | m2)];  Ai[7] = sim_[PHYS(bi | m0 | m1 | m2)];

      APPLY_GATES()

      sre[PHYS(bi)]                = Ar[0];  sim_[PHYS(bi)]                = Ai[0];
      sre[PHYS(bi | m0)]           = Ar[1];  sim_[PHYS(bi | m0)]           = Ai[1];
      sre[PHYS(bi | m1)]           = Ar[2];  sim_[PHYS(bi | m1)]           = Ai[2];
      sre[PHYS(bi | m0 | m1)]      = Ar[3];  sim_[PHYS(bi | m0 | m1)]      = Ai[3];
      sre[PHYS(bi | m2)]           = Ar[4];  sim_[PHYS(bi | m2)]           = Ai[4];
      sre[PHYS(bi | m0 | m2)]      = Ar[5];  sim_[PHYS(bi | m0 | m2)]      = Ai[5];
      sre[PHYS(bi | m1 | m2)]      = Ar[6];  sim_[PHYS(bi | m1 | m2)]      = Ai[6];
      sre[PHYS(bi | m0 | m1 | m2)] = Ar[7];  sim_[PHYS(bi | m0 | m1 | m2)] = Ai[7];
    }
    goff += ng;
    __syncthreads();
  }

  // --- peeled final cluster: gates + fused Z-expectation (no store) ---
  {
    const int ci = lcl[ncl - 1];
    const int q0 = ci & 255, q1 = (ci >> 8) & 255, q2 = (ci >> 16) & 255;
    const int ng = (ci >> 24) & 255;
    const int m0 = 1 << q0, m1 = 1 << q1, m2 = 1 << q2;

    #pragma unroll 1
    for (int grp = 0; grp < 2; ++grp) {
      int g = tid + (grp << 10);
      int bi = g;
      bi = ((bi >> q0) << (q0 + 1)) | (bi & (m0 - 1));
      bi = ((bi >> q1) << (q1 + 1)) | (bi & (m1 - 1));
      bi = ((bi >> q2) << (q2 + 1)) | (bi & (m2 - 1));

      float Ar[8], Ai[8];
      Ar[0] = sre[PHYS(bi)];                 Ai[0] = sim_[PHYS(bi)];
      Ar[1] = sre[PHYS(bi | m0)];            Ai[1] = sim_[PHYS(bi | m0)];
      Ar[2] = sre[PHYS(bi | m1)];            Ai[2] = sim_[PHYS(bi | m1)];
      Ar[3] = sre[PHYS(bi | m0 | m1)];       Ai[3] = sim_[PHYS(bi | m0 | m1)];
      Ar[4] = sre[PHYS(bi | m2)];            Ai[4] = sim_[PHYS(bi | m2)];
      Ar[5] = sre[PHYS(bi | m0 | m2)];       Ai[5] = sim_[PHYS(bi | m0 | m2)];
      Ar[6] = sre[PHYS(bi | m1 | m2)];       Ai[6] = sim_[PHYS(bi | m1 | m2)];
      Ar[7] = sre[PHYS(bi | m0 | m1 | m2)];  Ai[7] = sim_[PHYS(bi | m0 | m1 | m2)];

      APPLY_GATES()

      #pragma unroll
      for (int j = 0; j < 8; j++) {
        float p2 = Ar[j] * Ar[j] + Ai[j] * Ai[j];
        int idx = bi | ((j & 1) ? m0 : 0) | ((j & 2) ? m1 : 0) | ((j & 4) ? m2 : 0);
        #pragma unroll
        for (int w = 0; w < LATENT; w++)
          pr[w] += ((idx >> (13 - w)) & 1) ? -p2 : p2;
      }
    }
  }

  #pragma unroll
  for (int w = 0; w < LATENT; w++) {
    float v = pr[w];
    #pragma unroll
    for (int off = 32; off >= 1; off >>= 1) v += __shfl_down(v, off, 64);
    pr[w] = v;
  }
  __syncthreads();               // done with LDS state; reuse as reduction scratch
  float* red = sre;
  const int wave = tid >> 6, lane = tid & 63;
  if (lane == 0) {
    #pragma unroll
    for (int w = 0; w < LATENT; w++) red[wave * LATENT + w] = pr[w];
  }
  __syncthreads();
  if (tid < LATENT) {
    float v = 0.0f;
    #pragma unroll
    for (int wv = 0; wv < BLOCK / 64; wv++) v += red[wv * LATENT + tid];
    out[b * LATENT + tid] = v;
  }
}

extern "C" void kernel_launch(void* const* d_in, const int* in_sizes, int n_in,
                              void* d_out, int out_size, void* d_ws, size_t ws_size,
                              hipStream_t stream) {
  const float *x   = (const float*)d_in[0];   // [256*14] f32
  const float *rlp = (const float*)d_in[1];   // [50] f32
  float *out = (float*)d_out;                 // [256*8] f32

  Sched S;
  build_sched(S);                             // deterministic host work (capture-time)

  qae_k<<<dim3(BSZ), dim3(BLOCK), 0, stream>>>(x, rlp, out, S);
}

// Round 20
// 45.500 us; speedup vs baseline: 3.1075x; 1.7975x over previous
//
#include <hip/hip_runtime.h>
#include <cstdint>

#define N_WIRES 14
#define N_OPS   50
#define NSTATE  (1 << N_WIRES)   // 16384
#define BSZ     256
#define BLOCK   1024
#define LATENT  8
#define NCLMAX  50
#define LDSN    (NSTATE + (NSTATE >> 5))   // +1-per-32 padded
#define PHYS(i) ((i) + ((i) >> 5))

// ================= compile-time numpy RNG + schedule (verified round-13/14) =================
namespace cg {
typedef unsigned __int128 u128;
struct PCG { u128 state; u128 inc; bool has32; uint32_t buf32; };

constexpr u128 pcg_mult() {
  return (((u128)2549297995355413924ULL) << 64) | 4865540595714422341ULL;
}
constexpr uint64_t n64(PCG &s) {
  s.state = s.state * pcg_mult() + s.inc;
  uint64_t x = (uint64_t)(s.state >> 64) ^ (uint64_t)s.state;
  unsigned r = (unsigned)(s.state >> 122);
  return (x >> (r & 63)) | (x << ((64 - r) & 63));
}
constexpr uint32_t n32(PCG &s) {
  if (s.has32) { s.has32 = false; return s.buf32; }
  uint64_t n = n64(s);
  s.has32 = true; s.buf32 = (uint32_t)(n >> 32);
  return (uint32_t)n;
}
constexpr uint32_t hashmix(uint32_t v, uint32_t &hc) {
  v ^= hc; hc *= 0x931e8875u; v *= hc; v ^= v >> 16; return v;
}
constexpr uint32_t mixf(uint32_t x, uint32_t y) {
  uint32_t r = x * 0xca01f9ddu - y * 0x4973f715u;   // multiply-SUBTRACT (verified)
  r ^= r >> 16; return r;
}
constexpr PCG seedseq(uint32_t entropy) {
  uint32_t pool[4] = {0, 0, 0, 0};
  uint32_t hc = 0x43b0d7e5u;
  pool[0] = hashmix(entropy, hc);
  for (int i = 1; i < 4; i++) pool[i] = hashmix(0u, hc);
  for (int s = 0; s < 4; s++)
    for (int d = 0; d < 4; d++)
      if (s != d) pool[d] = mixf(pool[d], hashmix(pool[s], hc));
  uint32_t w[8] = {};
  uint32_t hb = 0x8b51f9ddu;
  for (int i = 0; i < 8; i++) {
    uint32_t dv = pool[i & 3];
    dv ^= hb; hb *= 0x58f38dedu; dv *= hb; dv ^= dv >> 16; w[i] = dv;
  }
  uint64_t v0 = (uint64_t)w[0] | ((uint64_t)w[1] << 32);
  uint64_t v1 = (uint64_t)w[2] | ((uint64_t)w[3] << 32);
  uint64_t v2 = (uint64_t)w[4] | ((uint64_t)w[5] << 32);
  uint64_t v3 = (uint64_t)w[6] | ((uint64_t)w[7] << 32);
  PCG r{};
  u128 initstate = ((u128)v0 << 64) | v1;
  u128 initseq   = ((u128)v2 << 64) | v3;
  r.inc = (initseq << 1) | 1;
  r.state = 0;
  r.state = r.state * pcg_mult() + r.inc;
  r.state += initstate;
  r.state = r.state * pcg_mult() + r.inc;
  r.has32 = false; r.buf32 = 0;
  return r;
}
constexpr uint32_t lem32(PCG &r, uint32_t rmax) {
  uint32_t ex = rmax + 1u;
  uint64_t m = (uint64_t)n32(r) * ex;
  uint32_t lo = (uint32_t)m;
  if (lo < ex) {
    uint32_t t = (0xFFFFFFFFu - rmax) % ex;
    while (lo < t) { m = (uint64_t)n32(r) * ex; lo = (uint32_t)m; }
  }
  return (uint32_t)(m >> 32);
}

struct SchedC {
  int ncl;
  int cpos[NCLMAX * 3];
  int cng[NCLMAX];
  int cgoff[NCLMAX];
  int gpk[N_OPS];     // type | la<<2 | lt<<4 | gidx<<6
};

constexpr SchedC make_sched() {
  // --- gatespec (winner mapping m=1, round-14 decode) ---
  int gt[N_OPS] = {}, g0[N_OPS] = {}, g1[N_OPS] = {};
  {
    PCG r = seedseq(1234u);
    for (int i = 0; i < N_OPS; i++) gt[i] = (int)lem32(r, 3);
    for (int i = 0; i < N_OPS; i++) {
      if (gt[i] < 3) { g0[i] = (int)lem32(r, 13); g1[i] = -1; continue; }
      uint32_t a = lem32(r, 12);
      uint32_t v = lem32(r, 13);
      uint32_t b = (v == a) ? 13u : v;
      uint32_t j = lem32(r, 1);
      if (j == 0) { uint32_t t = a; a = b; b = t; }
      g0[i] = (int)a; g1[i] = (int)b;
    }
  }
  // --- 3-wire frontier clustering (identical to verified r18 host code) ---
  SchedC S{};
  bool done[N_OPS] = {};
  int nsched = 0, ncl = 0, gcount = 0;
  while (nsched < N_OPS) {
    int posv[3] = {}, posn = 0;
    int clg[N_OPS] = {}, ncg = 0;
    bool progress = true;
    while (progress) {
      progress = false;
      for (int i = 0; i < N_OPS; i++) {
        if (done[i]) continue;
        bool avail = true;
        for (int j = 0; j < i && avail; j++) {
          if (done[j]) continue;
          if (g0[j] == g0[i] || (g1[i] >= 0 && g0[j] == g1[i])) avail = false;
          else if (g1[j] >= 0 && (g1[j] == g0[i] || (g1[i] >= 0 && g1[j] == g1[i]))) avail = false;
        }
        if (!avail) continue;
        int p0 = 13 - g0[i];
        int p1 = (g1[i] >= 0) ? (13 - g1[i]) : -1;
        bool h0 = false, h1 = (p1 < 0);
        for (int k = 0; k < posn; k++) {
          if (posv[k] == p0) h0 = true;
          if (p1 >= 0 && posv[k] == p1) h1 = true;
        }
        int need = (h0 ? 0 : 1) + ((p1 >= 0 && !h1) ? 1 : 0);
        if (posn + need > 3) continue;
        if (!h0) posv[posn++] = p0;
        if (p1 >= 0 && !h1) posv[posn++] = p1;
        clg[ncg++] = i;
        done[i] = true; nsched++; progress = true;
      }
    }
    for (int p = 0; posn < 3 && p < 14; p++) {
      bool used = false;
      for (int k = 0; k < posn; k++) if (posv[k] == p) used = true;
      if (!used) posv[posn++] = p;
    }
    for (int a = 0; a < 2; a++)
      for (int b2 = a + 1; b2 < 3; b2++)
        if (posv[b2] < posv[a]) { int t = posv[a]; posv[a] = posv[b2]; posv[b2] = t; }
    for (int k = 0; k < 3; k++) S.cpos[ncl * 3 + k] = posv[k];
    S.cng[ncl] = ncg;
    S.cgoff[ncl] = gcount;
    for (int e = 0; e < ncg; e++) {
      int i = clg[e];
      int pa = 13 - g0[i], la = 0;
      for (int k = 0; k < 3; k++) if (posv[k] == pa) la = k;
      int lt = 0;
      if (g1[i] >= 0) {
        int pt = 13 - g1[i];
        for (int k = 0; k < 3; k++) if (posv[k] == pt) lt = k;
      }
      S.gpk[gcount++] = gt[i] | (la << 2) | (lt << 4) | (i << 6);
    }
    ncl++;
  }
  S.ncl = ncl;
  return S;
}

constexpr SchedC SC = make_sched();
} // namespace cg

// ================= device: fully unrolled circuit =================
#define RXP(I0, I1) { float r0 = Ar[I0], q0_ = Ai[I0], r1 = Ar[I1], q1_ = Ai[I1]; \
  Ar[I0] = cc * r0 + ss * q1_; Ai[I0] = cc * q0_ - ss * r1; \
  Ar[I1] = cc * r1 + ss * q0_; Ai[I1] = cc * q1_ - ss * r0; }
#define RYP(I0, I1) { float r0 = Ar[I0], q0_ = Ai[I0], r1 = Ar[I1], q1_ = Ai[I1]; \
  Ar[I0] = cc * r0 - ss * r1; Ai[I0] = cc * q0_ - ss * q1_; \
  Ar[I1] = ss * r0 + cc * r1; Ai[I1] = ss * q0_ + cc * q1_; }
#define RZP(I0, I1) { float r0 = Ar[I0], q0_ = Ai[I0], r1 = Ar[I1], q1_ = Ai[I1]; \
  Ar[I0] = cc * r0 + ss * q0_; Ai[I0] = cc * q0_ - ss * r0; \
  Ar[I1] = cc * r1 - ss * q1_; Ai[I1] = cc * q1_ + ss * r1; }

template<int PK>
__device__ __forceinline__ void one_gate(float Ar[8], float Ai[8], const float2 *coef) {
  constexpr int t = PK & 3, la = (PK >> 2) & 3, lt = (PK >> 4) & 3, gi = PK >> 6;
  const float2 cs = coef[gi];
  const float cc = cs.x, ss = cs.y;
  if constexpr (t == 0) {
    if constexpr (la == 0)      { RXP(0,1) RXP(2,3) RXP(4,5) RXP(6,7) }
    else if constexpr (la == 1) { RXP(0,2) RXP(1,3) RXP(4,6) RXP(5,7) }
    else                        { RXP(0,4) RXP(1,5) RXP(2,6) RXP(3,7) }
  } else if constexpr (t == 1) {
    if constexpr (la == 0)      { RYP(0,1) RYP(2,3) RYP(4,5) RYP(6,7) }
    else if constexpr (la == 1) { RYP(0,2) RYP(1,3) RYP(4,6) RYP(5,7) }
    else                        { RYP(0,4) RYP(1,5) RYP(2,6) RYP(3,7) }
  } else if constexpr (t == 2) {
    if constexpr (la == 0)      { RZP(0,1) RZP(2,3) RZP(4,5) RZP(6,7) }
    else if constexpr (la == 1) { RZP(0,2) RZP(1,3) RZP(4,6) RZP(5,7) }
    else                        { RZP(0,4) RZP(1,5) RZP(2,6) RZP(3,7) }
  } else {
    constexpr int cse = la * 3 + lt;
    if constexpr (cse == 1)      { RXP(1,3) RXP(5,7) }
    else if constexpr (cse == 2) { RXP(1,5) RXP(3,7) }
    else if constexpr (cse == 3) { RXP(2,3) RXP(6,7) }
    else if constexpr (cse == 5) { RXP(2,6) RXP(3,7) }
    else if constexpr (cse == 6) { RXP(4,5) RXP(6,7) }
    else                         { RXP(4,6) RXP(5,7) }
  }
}

template<int GOFF, int NG, int E>
__device__ __forceinline__ void gates_rec(float Ar[8], float Ai[8], const float2 *coef) {
  if constexpr (E < NG) {
    one_gate<cg::SC.gpk[GOFF + E]>(Ar, Ai, coef);
    gates_rec<GOFF, NG, E + 1>(Ar, Ai, coef);
  }
}

template<int C>
__device__ __forceinline__ void do_cluster(float2 *st, const float2 *coef, int tid,
                                           float (&pr)[LATENT]) {
  constexpr int q0 = cg::SC.cpos[3 * C], q1 = cg::SC.cpos[3 * C + 1], q2 = cg::SC.cpos[3 * C + 2];
  constexpr int ng = cg::SC.cng[C], goff = cg::SC.cgoff[C];
  constexpr int m0 = 1 << q0, m1 = 1 << q1, m2 = 1 << q2;
  constexpr bool LAST = (C == cg::SC.ncl - 1);

  #pragma unroll 1                    // two 8-amp groups SEQUENTIAL (register cap)
  for (int grp = 0; grp < 2; ++grp) {
    int bi = tid + (grp << 10);
    bi = ((bi >> q0) << (q0 + 1)) | (bi & (m0 - 1));
    bi = ((bi >> q1) << (q1 + 1)) | (bi & (m1 - 1));
    bi = ((bi >> q2) << (q2 + 1)) | (bi & (m2 - 1));

    float Ar[8], Ai[8];
    { float2 v = st[PHYS(bi)];                Ar[0] = v.x; Ai[0] = v.y; }
    { float2 v = st[PHYS(bi | m0)];           Ar[1] = v.x; Ai[1] = v.y; }
    { float2 v = st[PHYS(bi | m1)];           Ar[2] = v.x; Ai[2] = v.y; }
    { float2 v = st[PHYS(bi | m0 | m1)];      Ar[3] = v.x; Ai[3] = v.y; }
    { float2 v = st[PHYS(bi | m2)];           Ar[4] = v.x; Ai[4] = v.y; }
    { float2 v = st[PHYS(bi | m0 | m2)];      Ar[5] = v.x; Ai[5] = v.y; }
    { float2 v = st[PHYS(bi | m1 | m2)];      Ar[6] = v.x; Ai[6] = v.y; }
    { float2 v = st[PHYS(bi | m0 | m1 | m2)]; Ar[7] = v.x; Ai[7] = v.y; }

    gates_rec<goff, ng, 0>(Ar, Ai, coef);

    if constexpr (!LAST) {
      st[PHYS(bi)]                = make_float2(Ar[0], Ai[0]);
      st[PHYS(bi | m0)]           = make_float2(Ar[1], Ai[1]);
      st[PHYS(bi | m1)]           = make_float2(Ar[2], Ai[2]);
      st[PHYS(bi | m0 | m1)]      = make_float2(Ar[3], Ai[3]);
      st[PHYS(bi | m2)]           = make_float2(Ar[4], Ai[4]);
      st[PHYS(bi | m0 | m2)]      = make_float2(Ar[5], Ai[5]);
      st[PHYS(bi | m1 | m2)]      = make_float2(Ar[6], Ai[6]);
      st[PHYS(bi | m0 | m1 | m2)] = make_float2(Ar[7], Ai[7]);
    } else {
      #pragma unroll
      for (int j = 0; j < 8; j++) {
        float p2 = Ar[j] * Ar[j] + Ai[j] * Ai[j];
        int idx = bi | ((j & 1) ? m0 : 0) | ((j & 2) ? m1 : 0) | ((j & 4) ? m2 : 0);
        #pragma unroll
        for (int w = 0; w < LATENT; w++)
          pr[w] += ((idx >> (13 - w)) & 1) ? -p2 : p2;
      }
    }
  }
  if constexpr (!LAST) __syncthreads();
}

template<int C>
__device__ __forceinline__ void clusters_rec(float2 *st, const float2 *coef, int tid,
                                             float (&pr)[LATENT]) {
  if constexpr (C < cg::SC.ncl) {
    do_cluster<C>(st, coef, tid, pr);
    clusters_rec<C + 1>(st, coef, tid, pr);
  }
}

__global__ __launch_bounds__(BLOCK) void qae_k(
    const float* __restrict__ x, const float* __restrict__ rlp,
    float* __restrict__ out)
{
  __shared__ float2 st[LDSN];                      // AoS: b64 LDS ops, half the DS count
  __shared__ float encc[N_WIRES], encs[N_WIRES];
  __shared__ float2 coef[N_OPS];
  const int b = blockIdx.x, tid = threadIdx.x;

  if (tid < N_WIRES) {
    float a = 0.5f * x[b * N_WIRES + tid];
    encc[tid] = cosf(a); encs[tid] = sinf(a);
  } else if (tid >= 64 && tid < 64 + N_OPS) {
    int g = tid - 64;
    float a = 0.5f * rlp[g];
    coef[g] = make_float2(cosf(a), sinf(a));
  }
  __syncthreads();

  // init sweep: product state (14 encoding RX gates fused), strided = conflict-free
  #pragma unroll 1
  for (int k = tid; k < NSTATE; k += BLOCK) {
    float r = 1.0f;
    #pragma unroll
    for (int p = 0; p < N_WIRES; p++)
      r *= ((k >> p) & 1) ? encs[13 - p] : encc[13 - p];
    int pc = __popc((unsigned)k) & 3;
    st[PHYS(k)] = make_float2((pc == 0) ? r : ((pc == 2) ? -r : 0.0f),
                              (pc == 1) ? -r : ((pc == 3) ? r : 0.0f));
  }
  __syncthreads();

  float pr[LATENT];
  #pragma unroll
  for (int w = 0; w < LATENT; w++) pr[w] = 0.0f;

  clusters_rec<0>(st, coef, tid, pr);              // the whole circuit, fully unrolled

  #pragma unroll
  for (int w = 0; w < LATENT; w++) {
    float v = pr[w];
    #pragma unroll
    for (int off = 32; off >= 1; off >>= 1) v += __shfl_down(v, off, 64);
    pr[w] = v;
  }
  __syncthreads();                                 // reuse st as reduction scratch
  float* red = (float*)st;
  const int wave = tid >> 6, lane = tid & 63;
  if (lane == 0) {
    #pragma unroll
    for (int w = 0; w < LATENT; w++) red[wave * LATENT + w] = pr[w];
  }
  __syncthreads();
  if (tid < LATENT) {
    float v = 0.0f;
    #pragma unroll
    for (int wv = 0; wv < BLOCK / 64; wv++) v += red[wv * LATENT + tid];
    out[b * LATENT + tid] = v;
  }
}

extern "C" void kernel_launch(void* const* d_in, const int* in_sizes, int n_in,
                              void* d_out, int out_size, void* d_ws, size_t ws_size,
                              hipStream_t stream) {
  const float *x   = (const float*)d_in[0];   // [256*14] f32
  const float *rlp = (const float*)d_in[1];   // [50] f32
  float *out = (float*)d_out;                 // [256*8] f32

  qae_k<<<dim3(BSZ), dim3(BLOCK), 0, stream>>>(x, rlp, out);
}

// Round 21
// 42.575 us; speedup vs baseline: 3.3210x; 1.0687x over previous
//
#include <hip/hip_runtime.h>
#include <cstdint>

#define N_WIRES 14
#define N_OPS   50
#define NSTATE  (1 << N_WIRES)   // 16384
#define BSZ     256
#define BLOCK   1024
#define LATENT  8
#define NCLMAX  50

// ================= compile-time numpy RNG + schedule (verified round-13/14) =================
namespace cg {
typedef unsigned __int128 u128;
struct PCG { u128 state; u128 inc; bool has32; uint32_t buf32; };

constexpr u128 pcg_mult() {
  return (((u128)2549297995355413924ULL) << 64) | 4865540595714422341ULL;
}
constexpr uint64_t n64(PCG &s) {
  s.state = s.state * pcg_mult() + s.inc;
  uint64_t x = (uint64_t)(s.state >> 64) ^ (uint64_t)s.state;
  unsigned r = (unsigned)(s.state >> 122);
  return (x >> (r & 63)) | (x << ((64 - r) & 63));
}
constexpr uint32_t n32(PCG &s) {
  if (s.has32) { s.has32 = false; return s.buf32; }
  uint64_t n = n64(s);
  s.has32 = true; s.buf32 = (uint32_t)(n >> 32);
  return (uint32_t)n;
}
constexpr uint32_t hashmix(uint32_t v, uint32_t &hc) {
  v ^= hc; hc *= 0x931e8875u; v *= hc; v ^= v >> 16; return v;
}
constexpr uint32_t mixf(uint32_t x, uint32_t y) {
  uint32_t r = x * 0xca01f9ddu - y * 0x4973f715u;   // multiply-SUBTRACT (verified)
  r ^= r >> 16; return r;
}
constexpr PCG seedseq(uint32_t entropy) {
  uint32_t pool[4] = {0, 0, 0, 0};
  uint32_t hc = 0x43b0d7e5u;
  pool[0] = hashmix(entropy, hc);
  for (int i = 1; i < 4; i++) pool[i] = hashmix(0u, hc);
  for (int s = 0; s < 4; s++)
    for (int d = 0; d < 4; d++)
      if (s != d) pool[d] = mixf(pool[d], hashmix(pool[s], hc));
  uint32_t w[8] = {};
  uint32_t hb = 0x8b51f9ddu;
  for (int i = 0; i < 8; i++) {
    uint32_t dv = pool[i & 3];
    dv ^= hb; hb *= 0x58f38dedu; dv *= hb; dv ^= dv >> 16; w[i] = dv;
  }
  uint64_t v0 = (uint64_t)w[0] | ((uint64_t)w[1] << 32);
  uint64_t v1 = (uint64_t)w[2] | ((uint64_t)w[3] << 32);
  uint64_t v2 = (uint64_t)w[4] | ((uint64_t)w[5] << 32);
  uint64_t v3 = (uint64_t)w[6] | ((uint64_t)w[7] << 32);
  PCG r{};
  u128 initstate = ((u128)v0 << 64) | v1;
  u128 initseq   = ((u128)v2 << 64) | v3;
  r.inc = (initseq << 1) | 1;
  r.state = 0;
  r.state = r.state * pcg_mult() + r.inc;
  r.state += initstate;
  r.state = r.state * pcg_mult() + r.inc;
  r.has32 = false; r.buf32 = 0;
  return r;
}
constexpr uint32_t lem32(PCG &r, uint32_t rmax) {
  uint32_t ex = rmax + 1u;
  uint64_t m = (uint64_t)n32(r) * ex;
  uint32_t lo = (uint32_t)m;
  if (lo < ex) {
    uint32_t t = (0xFFFFFFFFu - rmax) % ex;
    while (lo < t) { m = (uint64_t)n32(r) * ex; lo = (uint32_t)m; }
  }
  return (uint32_t)(m >> 32);
}

struct SchedC {
  int ncl;
  int cpos[NCLMAX * 3];
  int cng[NCLMAX];
  int cgoff[NCLMAX];
  int gpk[N_OPS];     // type | la<<2 | lt<<4 | gidx<<6
};

constexpr SchedC make_sched() {
  // --- gatespec (winner mapping m=1, round-14 decode) ---
  int gt[N_OPS] = {}, g0[N_OPS] = {}, g1[N_OPS] = {};
  {
    PCG r = seedseq(1234u);
    for (int i = 0; i < N_OPS; i++) gt[i] = (int)lem32(r, 3);
    for (int i = 0; i < N_OPS; i++) {
      if (gt[i] < 3) { g0[i] = (int)lem32(r, 13); g1[i] = -1; continue; }
      uint32_t a = lem32(r, 12);
      uint32_t v = lem32(r, 13);
      uint32_t b = (v == a) ? 13u : v;
      uint32_t j = lem32(r, 1);
      if (j == 0) { uint32_t t = a; a = b; b = t; }
      g0[i] = (int)a; g1[i] = (int)b;
    }
  }
  // --- 3-wire frontier clustering (identical to verified r18 host code) ---
  SchedC S{};
  bool done[N_OPS] = {};
  int nsched = 0, ncl = 0, gcount = 0;
  while (nsched < N_OPS) {
    int posv[3] = {}, posn = 0;
    int clg[N_OPS] = {}, ncg = 0;
    bool progress = true;
    while (progress) {
      progress = false;
      for (int i = 0; i < N_OPS; i++) {
        if (done[i]) continue;
        bool avail = true;
        for (int j = 0; j < i && avail; j++) {
          if (done[j]) continue;
          if (g0[j] == g0[i] || (g1[i] >= 0 && g0[j] == g1[i])) avail = false;
          else if (g1[j] >= 0 && (g1[j] == g0[i] || (g1[i] >= 0 && g1[j] == g1[i]))) avail = false;
        }
        if (!avail) continue;
        int p0 = 13 - g0[i];
        int p1 = (g1[i] >= 0) ? (13 - g1[i]) : -1;
        bool h0 = false, h1 = (p1 < 0);
        for (int k = 0; k < posn; k++) {
          if (posv[k] == p0) h0 = true;
          if (p1 >= 0 && posv[k] == p1) h1 = true;
        }
        int need = (h0 ? 0 : 1) + ((p1 >= 0 && !h1) ? 1 : 0);
        if (posn + need > 3) continue;
        if (!h0) posv[posn++] = p0;
        if (p1 >= 0 && !h1) posv[posn++] = p1;
        clg[ncg++] = i;
        done[i] = true; nsched++; progress = true;
      }
    }
    for (int p = 0; posn < 3 && p < 14; p++) {
      bool used = false;
      for (int k = 0; k < posn; k++) if (posv[k] == p) used = true;
      if (!used) posv[posn++] = p;
    }
    for (int a = 0; a < 2; a++)
      for (int b2 = a + 1; b2 < 3; b2++)
        if (posv[b2] < posv[a]) { int t = posv[a]; posv[a] = posv[b2]; posv[b2] = t; }
    for (int k = 0; k < 3; k++) S.cpos[ncl * 3 + k] = posv[k];
    S.cng[ncl] = ncg;
    S.cgoff[ncl] = gcount;
    for (int e = 0; e < ncg; e++) {
      int i = clg[e];
      int pa = 13 - g0[i], la = 0;
      for (int k = 0; k < 3; k++) if (posv[k] == pa) la = k;
      int lt = 0;
      if (g1[i] >= 0) {
        int pt = 13 - g1[i];
        for (int k = 0; k < 3; k++) if (posv[k] == pt) lt = k;
      }
      S.gpk[gcount++] = gt[i] | (la << 2) | (lt << 4) | (i << 6);
    }
    ncl++;
  }
  S.ncl = ncl;
  return S;
}

constexpr SchedC SC = make_sched();

// XOR nibble-fold swizzle on float2-index: conflict-free for all pow2 lane strides.
// XOR-linear: SWZ(a^b) = SWZ(a)^SWZ(b); identity for i<16.
constexpr int swzc(int i) { return i ^ (((i >> 4) ^ (i >> 8) ^ (i >> 12)) & 15); }
} // namespace cg

__device__ __forceinline__ int swzd(int i) {
  return i ^ (((i >> 4) ^ (i >> 8) ^ (i >> 12)) & 15);
}

// ================= device: fully unrolled circuit =================
#define RXP(I0, I1) { float r0 = Ar[I0], q0_ = Ai[I0], r1 = Ar[I1], q1_ = Ai[I1]; \
  Ar[I0] = cc * r0 + ss * q1_; Ai[I0] = cc * q0_ - ss * r1; \
  Ar[I1] = cc * r1 + ss * q0_; Ai[I1] = cc * q1_ - ss * r0; }
#define RYP(I0, I1) { float r0 = Ar[I0], q0_ = Ai[I0], r1 = Ar[I1], q1_ = Ai[I1]; \
  Ar[I0] = cc * r0 - ss * r1; Ai[I0] = cc * q0_ - ss * q1_; \
  Ar[I1] = ss * r0 + cc * r1; Ai[I1] = ss * q0_ + cc * q1_; }
#define RZP(I0, I1) { float r0 = Ar[I0], q0_ = Ai[I0], r1 = Ar[I1], q1_ = Ai[I1]; \
  Ar[I0] = cc * r0 + ss * q0_; Ai[I0] = cc * q0_ - ss * r0; \
  Ar[I1] = cc * r1 - ss * q1_; Ai[I1] = cc * q1_ + ss * r1; }

template<int PK>
__device__ __forceinline__ void one_gate(float Ar[8], float Ai[8], const float2 *coef) {
  constexpr int t = PK & 3, la = (PK >> 2) & 3, lt = (PK >> 4) & 3, gi = PK >> 6;
  const float2 cs = coef[gi];
  const float cc = cs.x, ss = cs.y;
  if constexpr (t == 0) {
    if constexpr (la == 0)      { RXP(0,1) RXP(2,3) RXP(4,5) RXP(6,7) }
    else if constexpr (la == 1) { RXP(0,2) RXP(1,3) RXP(4,6) RXP(5,7) }
    else                        { RXP(0,4) RXP(1,5) RXP(2,6) RXP(3,7) }
  } else if constexpr (t == 1) {
    if constexpr (la == 0)      { RYP(0,1) RYP(2,3) RYP(4,5) RYP(6,7) }
    else if constexpr (la == 1) { RYP(0,2) RYP(1,3) RYP(4,6) RYP(5,7) }
    else                        { RYP(0,4) RYP(1,5) RYP(2,6) RYP(3,7) }
  } else if constexpr (t == 2) {
    if constexpr (la == 0)      { RZP(0,1) RZP(2,3) RZP(4,5) RZP(6,7) }
    else if constexpr (la == 1) { RZP(0,2) RZP(1,3) RZP(4,6) RZP(5,7) }
    else                        { RZP(0,4) RZP(1,5) RZP(2,6) RZP(3,7) }
  } else {
    constexpr int cse = la * 3 + lt;
    if constexpr (cse == 1)      { RXP(1,3) RXP(5,7) }
    else if constexpr (cse == 2) { RXP(1,5) RXP(3,7) }
    else if constexpr (cse == 3) { RXP(2,3) RXP(6,7) }
    else if constexpr (cse == 5) { RXP(2,6) RXP(3,7) }
    else if constexpr (cse == 6) { RXP(4,5) RXP(6,7) }
    else                         { RXP(4,6) RXP(5,7) }
  }
}

template<int GOFF, int NG, int E>
__device__ __forceinline__ void gates_rec(float Ar[8], float Ai[8], const float2 *coef) {
  if constexpr (E < NG) {
    one_gate<cg::SC.gpk[GOFF + E]>(Ar, Ai, coef);
    gates_rec<GOFF, NG, E + 1>(Ar, Ai, coef);
  }
}

template<int C>
__device__ __forceinline__ void do_cluster(float2 *st, const float2 *coef, int tid,
                                           float (&pr)[LATENT]) {
  constexpr int q0 = cg::SC.cpos[3 * C], q1 = cg::SC.cpos[3 * C + 1], q2 = cg::SC.cpos[3 * C + 2];
  constexpr int ng = cg::SC.cng[C], goff = cg::SC.cgoff[C];
  constexpr int m0 = 1 << q0, m1 = 1 << q1, m2 = 1 << q2;
  constexpr bool LAST = (C == cg::SC.ncl - 1);
  // swizzled mask constants (SWZ is XOR-linear; bi and masks have disjoint bits)
  constexpr int s1 = cg::swzc(m0),           s2 = cg::swzc(m1);
  constexpr int s3 = cg::swzc(m0 | m1),      s4 = cg::swzc(m2);
  constexpr int s5 = cg::swzc(m0 | m2),      s6 = cg::swzc(m1 | m2);
  constexpr int s7 = cg::swzc(m0 | m1 | m2);

  #pragma unroll 1                    // two 8-amp groups SEQUENTIAL (register cap)
  for (int grp = 0; grp < 2; ++grp) {
    int bi = tid + (grp << 10);
    bi = ((bi >> q0) << (q0 + 1)) | (bi & (m0 - 1));
    bi = ((bi >> q1) << (q1 + 1)) | (bi & (m1 - 1));
    bi = ((bi >> q2) << (q2 + 1)) | (bi & (m2 - 1));
    const int sb = swzd(bi);

    float Ar[8], Ai[8];
    { float2 v = st[sb];      Ar[0] = v.x; Ai[0] = v.y; }
    { float2 v = st[sb ^ s1]; Ar[1] = v.x; Ai[1] = v.y; }
    { float2 v = st[sb ^ s2]; Ar[2] = v.x; Ai[2] = v.y; }
    { float2 v = st[sb ^ s3]; Ar[3] = v.x; Ai[3] = v.y; }
    { float2 v = st[sb ^ s4]; Ar[4] = v.x; Ai[4] = v.y; }
    { float2 v = st[sb ^ s5]; Ar[5] = v.x; Ai[5] = v.y; }
    { float2 v = st[sb ^ s6]; Ar[6] = v.x; Ai[6] = v.y; }
    { float2 v = st[sb ^ s7]; Ar[7] = v.x; Ai[7] = v.y; }

    gates_rec<goff, ng, 0>(Ar, Ai, coef);

    if constexpr (!LAST) {
      st[sb]      = make_float2(Ar[0], Ai[0]);
      st[sb ^ s1] = make_float2(Ar[1], Ai[1]);
      st[sb ^ s2] = make_float2(Ar[2], Ai[2]);
      st[sb ^ s3] = make_float2(Ar[3], Ai[3]);
      st[sb ^ s4] = make_float2(Ar[4], Ai[4]);
      st[sb ^ s5] = make_float2(Ar[5], Ai[5]);
      st[sb ^ s6] = make_float2(Ar[6], Ai[6]);
      st[sb ^ s7] = make_float2(Ar[7], Ai[7]);
    } else {
      #pragma unroll
      for (int j = 0; j < 8; j++) {
        float p2 = Ar[j] * Ar[j] + Ai[j] * Ai[j];
        int idx = bi | ((j & 1) ? m0 : 0) | ((j & 2) ? m1 : 0) | ((j & 4) ? m2 : 0);
        #pragma unroll
        for (int w = 0; w < LATENT; w++)
          pr[w] += ((idx >> (13 - w)) & 1) ? -p2 : p2;
      }
    }
  }
  if constexpr (!LAST) __syncthreads();
}

template<int C>
__device__ __forceinline__ void clusters_rec(float2 *st, const float2 *coef, int tid,
                                             float (&pr)[LATENT]) {
  if constexpr (C < cg::SC.ncl) {
    do_cluster<C>(st, coef, tid, pr);
    clusters_rec<C + 1>(st, coef, tid, pr);
  }
}

__global__ __launch_bounds__(BLOCK) void qae_k(
    const float* __restrict__ x, const float* __restrict__ rlp,
    float* __restrict__ out)
{
  __shared__ float2 st[NSTATE];                    // swizzled layout, no padding
  __shared__ float encc[N_WIRES], encs[N_WIRES];
  __shared__ float2 coef[N_OPS];
  const int b = blockIdx.x, tid = threadIdx.x;

  if (tid < N_WIRES) {
    float a = 0.5f * x[b * N_WIRES + tid];
    encc[tid] = cosf(a); encs[tid] = sinf(a);
  } else if (tid >= 64 && tid < 64 + N_OPS) {
    int g = tid - 64;
    float a = 0.5f * rlp[g];
    coef[g] = make_float2(cosf(a), sinf(a));
  }
  __syncthreads();

  // init sweep: product state (14 encoding RX gates fused); swizzled store
  #pragma unroll 1
  for (int k = tid; k < NSTATE; k += BLOCK) {
    float r = 1.0f;
    #pragma unroll
    for (int p = 0; p < N_WIRES; p++)
      r *= ((k >> p) & 1) ? encs[13 - p] : encc[13 - p];
    int pc = __popc((unsigned)k) & 3;
    st[swzd(k)] = make_float2((pc == 0) ? r : ((pc == 2) ? -r : 0.0f),
                              (pc == 1) ? -r : ((pc == 3) ? r : 0.0f));
  }
  __syncthreads();

  float pr[LATENT];
  #pragma unroll
  for (int w = 0; w < LATENT; w++) pr[w] = 0.0f;

  clusters_rec<0>(st, coef, tid, pr);              // the whole circuit, fully unrolled

  #pragma unroll
  for (int w = 0; w < LATENT; w++) {
    float v = pr[w];
    #pragma unroll
    for (int off = 32; off >= 1; off >>= 1) v += __shfl_down(v, off, 64);
    pr[w] = v;
  }
  __syncthreads();                                 // reuse st as reduction scratch
  float* red = (float*)st;
  const int wave = tid >> 6, lane = tid & 63;
  if (lane == 0) {
    #pragma unroll
    for (int w = 0; w < LATENT; w++) red[wave * LATENT + w] = pr[w];
  }
  __syncthreads();
  if (tid < LATENT) {
    float v = 0.0f;
    #pragma unroll
    for (int wv = 0; wv < BLOCK / 64; wv++) v += red[wv * LATENT + tid];
    out[b * LATENT + tid] = v;
  }
}

extern "C" void kernel_launch(void* const* d_in, const int* in_sizes, int n_in,
                              void* d_out, int out_size, void* d_ws, size_t ws_size,
                              hipStream_t stream) {
  const float *x   = (const float*)d_in[0];   // [256*14] f32
  const float *rlp = (const float*)d_in[1];   // [50] f32
  float *out = (float*)d_out;                 // [256*8] f32

  qae_k<<<dim3(BSZ), dim3(BLOCK), 0, stream>>>(x, rlp, out);
}